// Round 6
// baseline (2992.624 us; speedup 1.0000x reference)
//
#include <hip/hip_runtime.h>

#define N_NODES 100000
#define N_EDGES 600000
#define NPAD    100096      // 782 * 128
#define NTILES  782
#define SCAN_B  98          // ceil(100000/1024)
#define EPS_F   1e-5f
#define GRIDG   512         // persistent mixed grid: 2 blocks (16 waves) per CU

typedef __bf16 bf16_t;
typedef __bf16 bf16x8 __attribute__((ext_vector_type(8)));
typedef __bf16 bf16x4 __attribute__((ext_vector_type(4)));
typedef float  f32x4  __attribute__((ext_vector_type(4)));

// ---------------------------------------------------------------------------
// zero deg + grid-barrier counters
__global__ __launch_bounds__(256)
void init_zero_kernel(int* __restrict__ deg, int* __restrict__ cnt)
{
    int i = blockIdx.x * 256 + threadIdx.x;
    if (i < N_NODES) deg[i] = 0;
    if (i < 32) cnt[i] = 0;
}

// ---------------------------------------------------------------------------
// Weight pre-transpose: WT[mat][n][k] = W[mat][k][n], fp32 -> bf16.
__global__ __launch_bounds__(256)
void transpose_w_kernel(const float* __restrict__ Wz, const float* __restrict__ Wf,
                        const float* __restrict__ Wm, const float* __restrict__ Wl,
                        const float* __restrict__ Wc, bf16_t* __restrict__ wt)
{
    int idx = blockIdx.x * 256 + threadIdx.x;      // < 27*16384, exact grid
    int mat = idx >> 14;
    int off = idx & 16383;
    int n = off >> 7, kk = off & 127;
    const float* src;
    if      (mat < 3)  src = Wz + mat * 16384;
    else if (mat < 12) src = Wf + (mat - 3) * 16384;
    else if (mat < 18) src = Wm + (mat - 12) * 16384;
    else if (mat < 24) src = Wl + (mat - 18) * 16384;
    else               src = Wc + (mat - 24) * 16384;
    wt[idx] = (bf16_t)src[kk * 128 + n];
}

// ---------------------------------------------------------------------------
// pre-candidates, vectorized 8 elems/thread: [se, se-hr, se*hr] as bf16
__global__ __launch_bounds__(256)
void pre_kernel(const float* __restrict__ se, const float* __restrict__ hr,
                bf16_t* __restrict__ p0, bf16_t* __restrict__ p1, bf16_t* __restrict__ p2)
{
    long i = ((long)blockIdx.x * 256 + threadIdx.x) * 8;   // grid exact: N*128/2048
    float4 a0 = *(const float4*)&se[i], a1 = *(const float4*)&se[i + 4];
    float4 b0 = *(const float4*)&hr[i], b1 = *(const float4*)&hr[i + 4];
    float av[8] = {a0.x, a0.y, a0.z, a0.w, a1.x, a1.y, a1.z, a1.w};
    float bv[8] = {b0.x, b0.y, b0.z, b0.w, b1.x, b1.y, b1.z, b1.w};
    bf16x8 o0, o1, o2;
#pragma unroll
    for (int j = 0; j < 8; ++j) {
        o0[j] = (bf16_t)av[j];
        o1[j] = (bf16_t)(av[j] - bv[j]);
        o2[j] = (bf16_t)(av[j] * bv[j]);
    }
    *(bf16x8*)&p0[i] = o0;
    *(bf16x8*)&p1[i] = o1;
    *(bf16x8*)&p2[i] = o2;
}

// ---------------------------------------------------------------------------
// CSR build
__global__ __launch_bounds__(256)
void deg_count_kernel(const int* __restrict__ dst, int* __restrict__ deg)
{
    int i = blockIdx.x * 256 + threadIdx.x;
    if (i < N_EDGES) atomicAdd(&deg[dst[i]], 1);
}

__global__ __launch_bounds__(256)
void scan_a_kernel(const int* __restrict__ deg, int* __restrict__ partials)
{
    __shared__ int ls[256];
    int b = blockIdx.x, t = threadIdx.x;
    int s = 0;
    for (int j = 0; j < 4; ++j) {
        int i = b * 1024 + t * 4 + j;
        if (i < N_NODES) s += deg[i];
    }
    ls[t] = s; __syncthreads();
    for (int o = 128; o > 0; o >>= 1) {
        if (t < o) ls[t] += ls[t + o];
        __syncthreads();
    }
    if (t == 0) partials[b] = ls[0];
}

__global__ void scan_b_kernel(const int* __restrict__ partials, int* __restrict__ pofs)
{
    if (threadIdx.x == 0) {
        int a = 0;
        for (int i = 0; i < SCAN_B; ++i) { pofs[i] = a; a += partials[i]; }
    }
}

__global__ __launch_bounds__(256)
void scan_c_kernel(const int* __restrict__ deg, const int* __restrict__ pofs,
                   int* __restrict__ row_ptr, int* __restrict__ cursor)
{
    __shared__ int ls[256];
    int b = blockIdx.x, t = threadIdx.x;
    int v[4], s = 0;
    for (int j = 0; j < 4; ++j) {
        int i = b * 1024 + t * 4 + j;
        v[j] = (i < N_NODES) ? deg[i] : 0;
        s += v[j];
    }
    ls[t] = s; __syncthreads();
    for (int o = 1; o < 256; o <<= 1) {
        int tv = (t >= o) ? ls[t - o] : 0;
        __syncthreads();
        ls[t] += tv;
        __syncthreads();
    }
    int excl = ls[t] - s + pofs[b];
    for (int j = 0; j < 4; ++j) {
        int i = b * 1024 + t * 4 + j;
        if (i < N_NODES) { row_ptr[i] = excl; cursor[i] = excl; excl += v[j]; }
    }
    if (b == 0 && t == 0) row_ptr[N_NODES] = N_EDGES;
}

__global__ __launch_bounds__(256)
void scatter_kernel(const int* __restrict__ src, const int* __restrict__ dst,
                    int* __restrict__ cursor, int* __restrict__ csr_src)
{
    int i = blockIdx.x * 256 + threadIdx.x;
    if (i < N_EDGES) {
        int p = atomicAdd(&cursor[dst[i]], 1);
        csr_src[p] = src[i];
    }
}

// ---------------------------------------------------------------------------
// mean + max aggregation. 16 lanes per node, 16B loads per lane per edge.
__global__ __launch_bounds__(256)
void agg_kernel(const bf16_t* __restrict__ h, const int* __restrict__ row_ptr,
                const int* __restrict__ csr_src,
                bf16_t* __restrict__ mean_o, bf16_t* __restrict__ max_o)
{
    int node = blockIdx.x * 16 + (threadIdx.x >> 4);   // grid exact: N/16
    int dd = (threadIdx.x & 15) * 8;
    int e0 = row_ptr[node], e1 = row_ptr[node + 1];
    float s[8], mx[8];
#pragma unroll
    for (int j = 0; j < 8; ++j) { s[j] = 0.f; mx[j] = 0.f; }
    for (int e = e0; e < e1; ++e) {
        int sc = csr_src[e];
        bf16x8 v = *(const bf16x8*)&h[(long)sc * 128 + dd];
#pragma unroll
        for (int j = 0; j < 8; ++j) {
            float f = (float)v[j];
            s[j] += f;
            mx[j] = fmaxf(mx[j], f);
        }
    }
    float inv = 1.f / fmaxf((float)(e1 - e0), 1.f);
    bf16x8 om, ox;
#pragma unroll
    for (int j = 0; j < 8; ++j) { om[j] = (bf16_t)(s[j] * inv); ox[j] = (bf16_t)mx[j]; }
    *(bf16x8*)&mean_o[(long)node * 128 + dd] = om;
    *(bf16x8*)&max_o [(long)node * 128 + dd] = ox;
}

// ---------------------------------------------------------------------------
// async global->LDS, 16B per lane. LDS dest must be wave-uniform base + lane*16.
__device__ __forceinline__ void gload_lds16(const bf16_t* g, bf16_t* l)
{
    __builtin_amdgcn_global_load_lds(
        (const __attribute__((address_space(1))) void*)g,
        (__attribute__((address_space(3))) void*)l, 16, 0, 0);
}

// lgkm-only barrier: orders LDS writes->reads across waves WITHOUT draining vmcnt.
__device__ __forceinline__ void barrier_lgkm()
{
    asm volatile("s_waitcnt lgkmcnt(0)" ::: "memory");
    __builtin_amdgcn_s_barrier();
    asm volatile("" ::: "memory");
}

// device-wide barrier (R4-proven): RELAXED spin (no per-iteration cache inv),
// one release fence pre-arrival, one acquire fence post-exit, only where used.
// SAFETY: LDS 67KB => exactly 2 blocks/CU; grid==512==2*#CUs and
// __launch_bounds__(512,4) caps VGPR at 128 (16 waves/CU fit) => all blocks
// co-resident BY CONSTRUCTION. Counters pre-zeroed per launch.
__device__ __forceinline__ void grid_bar(int* c, int do_rel, int do_acq)
{
    __syncthreads();
    if (threadIdx.x == 0) {
        if (do_rel) __builtin_amdgcn_fence(__ATOMIC_RELEASE, "agent");
        __hip_atomic_fetch_add(c, 1, __ATOMIC_RELAXED, __HIP_MEMORY_SCOPE_AGENT);
        while (__hip_atomic_load(c, __ATOMIC_RELAXED, __HIP_MEMORY_SCOPE_AGENT) < GRIDG)
            __builtin_amdgcn_s_sleep(16);
        if (do_acq) __builtin_amdgcn_fence(__ATOMIC_ACQUIRE, "agent");
    }
    __syncthreads();
}

// ---------------------------------------------------------------------------
// Fused mixed-op kernel, v3 (2 blocks/CU TLP + double-buffered DMA):
//   R5 lesson: 1 block/CU persistent variants cap at 0.5-1.3 TB/s regardless
//   of ring depth; every 2-block/CU config (R0/R2) sustains ~2.3 TB/s. So:
//   GRIDG=512 (2 blocks/CU), x double buffer (2 x 32KB), vmcnt(0)+barrier per
//   item; while one block waits, the other computes (TLP hides DMA latency).
//   W in registers (wreg[3][2][4]); launch_bounds(512,4) caps VGPR at 128 so
//   2 blocks/CU is GUARANTEED (grid_bar liveness depends on it).
//   Stats in registers (raw acc; bias folded analytically at coef build).
// Phase A: stats only. grid_bar -> nk*32-block fold -> grid_bar -> coefs.
// Phase B: tile-major recompute, emit state=sum_c relu(A_c*acc+B_c) bf16
//   (mode 0) or final fp32 (mode 1).
__global__ __launch_bounds__(512, 4)
void mixed_kernel(const bf16_t* __restrict__ x0, const bf16_t* __restrict__ x1,
                  const bf16_t* __restrict__ x2, const bf16_t* __restrict__ wt,
                  const float* __restrict__ bias, const float* __restrict__ gg,
                  const float* __restrict__ be, const float* __restrict__ wmix,
                  bf16_t* __restrict__ outb, float* __restrict__ outf,
                  float* __restrict__ partial, float* __restrict__ tmp,
                  int* __restrict__ cnt, int mode, int accflag)
{
    __shared__ __align__(16) bf16_t lds_x[2][16384];   // x double buffer (64 KB)
    __shared__ float lsc[768];                         // lred / coefs (3 KB)

    const int tid  = threadIdx.x;
    const int lane = tid & 63;
    const int w8   = tid >> 6;
    const int quad = lane >> 4;
    const int t16  = lane & 15;
    const int wr = w8 >> 2, wc = w8 & 3;
    const int bid = blockIdx.x;
    const float invN = 1.0f / (float)N_NODES;

    // staging offsets: linear LDS dest, XOR swizzle in the global source
    int srcoff[4], dsto[4];
#pragma unroll
    for (int i = 0; i < 4; ++i) {
        int ci = i * 512 + tid;
        int row = ci >> 4, c = ci & 15;
        srcoff[i] = row * 128 + ((c ^ (row & 15)) * 8);
        dsto[i]   = ci * 8;
    }
    auto stage = [&](const bf16_t* src, int slot) {
#pragma unroll
        for (int i = 0; i < 4; ++i)
            gload_lds16(src + srcoff[i], &lds_x[slot][dsto[i]]);
    };
    auto xp = [&](int c) { return (c == 0) ? x0 : (c == 1) ? x1 : x2; };

    // W fragments to registers (global, L2-hot; swizzle-free layout)
    bf16x8 wreg[3][2][4];
#pragma unroll
    for (int c = 0; c < 3; ++c)
#pragma unroll
        for (int ns = 0; ns < 2; ++ns)
#pragma unroll
            for (int ks = 0; ks < 4; ++ks)
                wreg[c][ns][ks] = *(const bf16x8*)
                    &wt[(long)c * 16384 + (wc * 32 + ns * 16 + t16) * 128
                        + ks * 32 + quad * 8];

    const int ts = (int)(((long)bid * NTILES) / GRIDG);
    const int te = (int)(((long)(bid + 1) * NTILES) / GRIDG);
    const int nk = (mode == 0) ? 3 : 1;

    f32x4 acc[2][4];
    float ssA[3][8], sqA[3][8];
#pragma unroll
    for (int k = 0; k < 3; ++k)
#pragma unroll
        for (int i = 0; i < 8; ++i) { ssA[k][i] = 0.f; sqA[k][i] = 0.f; }

#define ZACC() do { \
    _Pragma("unroll") for (int a_ = 0; a_ < 2; ++a_) \
    _Pragma("unroll") for (int b_ = 0; b_ < 4; ++b_) \
        acc[a_][b_] = (f32x4){0.f, 0.f, 0.f, 0.f}; } while (0)

#define MMAC(C) do { \
    _Pragma("unroll") for (int ks = 0; ks < 4; ++ks) { \
        bf16x8 xf[4]; \
        _Pragma("unroll") for (int ms = 0; ms < 4; ++ms) { \
            int row_ = wr * 64 + ms * 16 + t16; \
            int sw_ = (ks * 4 + quad) ^ t16; \
            xf[ms] = *(const bf16x8*)&lds_x[slot][row_ * 128 + sw_ * 8]; \
        } \
        _Pragma("unroll") for (int ns = 0; ns < 2; ++ns) \
        _Pragma("unroll") for (int ms = 0; ms < 4; ++ms) \
            acc[ns][ms] = __builtin_amdgcn_mfma_f32_16x16x32_bf16( \
                wreg[C][ns][ks], xf[ms], acc[ns][ms], 0, 0, 0); \
    } } while (0)

#define ACCST(K) do { \
    _Pragma("unroll") for (int ms = 0; ms < 4; ++ms) { \
        long m_ = (long)tile * 128 + wr * 64 + ms * 16 + t16; \
        if (m_ < N_NODES) { \
            _Pragma("unroll") for (int ns = 0; ns < 2; ++ns) \
            _Pragma("unroll") for (int j_ = 0; j_ < 4; ++j_) { \
                float v_ = acc[ns][ms][j_]; \
                ssA[K][ns * 4 + j_] += v_; \
                sqA[K][ns * 4 + j_] += v_ * v_; \
            } \
        } \
    } } while (0)

// double-buffer wait: slot-w data ready (per-wave vmcnt BEFORE barrier =>
// after barrier ALL waves' portions are complete)
#define DBWAIT() do { \
    asm volatile("s_waitcnt vmcnt(0)" ::: "memory"); \
    __builtin_amdgcn_sched_barrier(0); \
    __builtin_amdgcn_s_barrier(); \
    __builtin_amdgcn_sched_barrier(0); } while (0)

    // ---------------- Phase A: stats only ----------------
    {
        int sA, eA;
        if (mode == 0) {   // item-balanced (items independent)
            sA = (int)(((long)bid * (NTILES * 3)) / GRIDG);
            eA = (int)(((long)(bid + 1) * (NTILES * 3)) / GRIDG);
        } else {           // tile-aligned (acc chained over c)
            sA = ts * 3; eA = te * 3;
        }
        stage(xp(sA % 3) + (long)(sA / 3) * 16384, sA & 1);
#pragma unroll 1
        for (int w = sA; w < eA; ++w) {
            const int c = w % 3, tile = w / 3, slot = w & 1;
            DBWAIT();
            if (w + 1 < eA)
                stage(xp((w + 1) % 3) + (long)((w + 1) / 3) * 16384, (w + 1) & 1);
            if (mode == 0 || c == 0) ZACC();
            if (c == 0) MMAC(0); else if (c == 1) MMAC(1); else MMAC(2);
            if (mode == 0) {
                if (c == 0) ACCST(0); else if (c == 1) ACCST(1); else ACCST(2);
            } else if (c == 2) ACCST(0);
        }
    }

    // block-level stats reduce: shfl over the 16 lanes of each t16 group
#pragma unroll
    for (int o = 1; o < 16; o <<= 1)
#pragma unroll
        for (int k = 0; k < 3; ++k)
#pragma unroll
            for (int i = 0; i < 8; ++i) {
                ssA[k][i] += __shfl_xor(ssA[k][i], o);
                sqA[k][i] += __shfl_xor(sqA[k][i], o);
            }
#pragma unroll 1
    for (int k = 0; k < nk; ++k) {
        barrier_lgkm();                        // lsc reuse fence
        if (t16 == 0) {
#pragma unroll
            for (int ns = 0; ns < 2; ++ns)
#pragma unroll
                for (int i = 0; i < 4; ++i) {
                    float s_, q_;
                    if (k == 0)      { s_ = ssA[0][ns*4+i]; q_ = sqA[0][ns*4+i]; }
                    else if (k == 1) { s_ = ssA[1][ns*4+i]; q_ = sqA[1][ns*4+i]; }
                    else             { s_ = ssA[2][ns*4+i]; q_ = sqA[2][ns*4+i]; }
                    lsc[w8 * 64 +      ns * 16 + quad * 4 + i] = s_;
                    lsc[w8 * 64 + 32 + ns * 16 + quad * 4 + i] = q_;
                }
        }
        barrier_lgkm();
        if (tid < 256) {
            int selo = (tid >> 7) * 32;
            int d = tid & 127;
            int wcq = d >> 5, f = d & 31;
            float v = lsc[wcq * 64 + selo + f] + lsc[(wcq + 4) * 64 + selo + f];
            partial[((long)k * GRIDG + bid) * 256 + tid] = v;
        }
    }

    // ---------------- stats fold + coefficients ----------------
    const int foldblk = (bid < nk * 32);
    grid_bar(cnt + 0, 1, foldblk);
    if (foldblk && tid < 256) {                // sum 16 block-rows each
        int k = bid >> 5, j = bid & 31;
        float s = 0.f;
        const float* pp = partial + ((long)k * GRIDG + j * 16) * 256 + tid;
#pragma unroll
        for (int b = 0; b < 16; ++b) s += pp[(long)b * 256];
        tmp[(k * 32 + j) * 256 + tid] = s;
    }
    grid_bar(cnt + 1, foldblk, 1);
    if (tid < 128) {                           // per-block coef build
        for (int k = 0; k < nk; ++k) {
            float S = 0.f, Q = 0.f;
#pragma unroll
            for (int j = 0; j < 32; ++j) {
                S += tmp[(k * 32 + j) * 256 + tid];
                Q += tmp[(k * 32 + j) * 256 + 128 + tid];
            }
            float sa  = S * invN;              // mean of raw acc
            float var = Q * invN - sa * sa;    // bias shift: variance unchanged
            float rs  = rsqrtf(var + EPS_F);
            float gk = gg[k * 128 + tid], bek = be[k * 128 + tid];
            float wk = (mode == 0) ? wmix[k] : 1.f;
            lsc[k * 256 + tid]       = wk * rs * gk;              // A
            lsc[k * 256 + 128 + tid] = wk * (-sa * rs * gk + bek);// B (b-mu=-sa)
        }
    }
    __syncthreads();

    // ---------------- Phase B: recompute + emit ----------------
    {
        const int w0 = ts * 3, w1 = te * 3;
        f32x4 res[2][4];
        stage(xp(w0 % 3) + (long)(w0 / 3) * 16384, w0 & 1);
#pragma unroll 1
        for (int w = w0; w < w1; ++w) {
            const int c = w % 3, tile = w / 3, slot = w & 1;
            DBWAIT();
            // res preload BEFORE the prefetch issue so its vmcnt wait does not
            // drain the in-flight stage (vmcnt retires in order)
            if (mode == 0 && c == 0) {
                if (accflag) {
#pragma unroll
                    for (int ns = 0; ns < 2; ++ns)
#pragma unroll
                        for (int ms = 0; ms < 4; ++ms) {
                            long m = (long)tile * 128 + wr * 64 + ms * 16 + t16;
                            int n0 = wc * 32 + ns * 16 + quad * 4;
                            bf16x4 pv = *(const bf16x4*)&outb[m * 128 + n0];
                            res[ns][ms] = (f32x4){(float)pv[0], (float)pv[1],
                                                  (float)pv[2], (float)pv[3]};
                        }
                } else {
#pragma unroll
                    for (int a = 0; a < 2; ++a)
#pragma unroll
                        for (int b = 0; b < 4; ++b) res[a][b] = (f32x4){0.f, 0.f, 0.f, 0.f};
                }
            }
            if (w + 1 < w1)
                stage(xp((w + 1) % 3) + (long)((w + 1) / 3) * 16384, (w + 1) & 1);
            if (mode == 0 || c == 0) ZACC();
            if (c == 0) MMAC(0); else if (c == 1) MMAC(1); else MMAC(2);

            if (mode == 0) {
#pragma unroll
                for (int ns = 0; ns < 2; ++ns) {
                    int n0 = wc * 32 + ns * 16 + quad * 4;
                    float4 A4 = *(const float4*)&lsc[c * 256 + n0];
                    float4 B4 = *(const float4*)&lsc[c * 256 + 128 + n0];
#pragma unroll
                    for (int ms = 0; ms < 4; ++ms) {
                        res[ns][ms][0] += fmaxf(acc[ns][ms][0] * A4.x + B4.x, 0.f);
                        res[ns][ms][1] += fmaxf(acc[ns][ms][1] * A4.y + B4.y, 0.f);
                        res[ns][ms][2] += fmaxf(acc[ns][ms][2] * A4.z + B4.z, 0.f);
                        res[ns][ms][3] += fmaxf(acc[ns][ms][3] * A4.w + B4.w, 0.f);
                    }
                }
                if (c == 2) {
#pragma unroll
                    for (int ms = 0; ms < 4; ++ms) {
                        long m = (long)tile * 128 + wr * 64 + ms * 16 + t16;
                        if (m < N_NODES) {
#pragma unroll
                            for (int ns = 0; ns < 2; ++ns) {
                                int n0 = wc * 32 + ns * 16 + quad * 4;
                                bf16x4 ov;
                                ov[0] = (bf16_t)res[ns][ms][0];
                                ov[1] = (bf16_t)res[ns][ms][1];
                                ov[2] = (bf16_t)res[ns][ms][2];
                                ov[3] = (bf16_t)res[ns][ms][3];
                                *(bf16x4*)&outb[m * 128 + n0] = ov;
                            }
                        }
                    }
                }
            } else if (c == 2) {
#pragma unroll
                for (int ms = 0; ms < 4; ++ms) {
                    long m = (long)tile * 128 + wr * 64 + ms * 16 + t16;
                    if (m < N_NODES) {
#pragma unroll
                        for (int ns = 0; ns < 2; ++ns) {
                            int n0 = wc * 32 + ns * 16 + quad * 4;
                            float4 A4 = *(const float4*)&lsc[n0];
                            float4 B4 = *(const float4*)&lsc[128 + n0];
                            float4 o;
                            o.x = fmaxf(acc[ns][ms][0] * A4.x + B4.x, 0.f);
                            o.y = fmaxf(acc[ns][ms][1] * A4.y + B4.y, 0.f);
                            o.z = fmaxf(acc[ns][ms][2] * A4.z + B4.z, 0.f);
                            o.w = fmaxf(acc[ns][ms][3] * A4.w + B4.w, 0.f);
                            *(float4*)&outf[m * 128 + n0] = o;
                        }
                    }
                }
            }
        }
    }
#undef ZACC
#undef MMAC
#undef ACCST
#undef DBWAIT
}

// ---------------------------------------------------------------------------
extern "C" void kernel_launch(void* const* d_in, const int* in_sizes, int n_in,
                              void* d_out, int out_size, void* d_ws, size_t ws_size,
                              hipStream_t stream)
{
    const float* src_emb = (const float*)d_in[0];
    const float* hr      = (const float*)d_in[1];
    const int*   e_src   = (const int*)d_in[2];
    const int*   e_dst   = (const int*)d_in[3];
    const float* w_zero  = (const float*)d_in[4];
    const float* w_first = (const float*)d_in[5];
    const float* w_mid   = (const float*)d_in[6];
    const float* w_last  = (const float*)d_in[7];
    const float* W_zero  = (const float*)d_in[8];
    const float* b_zero  = (const float*)d_in[9];
    const float* g_zero  = (const float*)d_in[10];
    const float* be_zero = (const float*)d_in[11];
    const float* W_first = (const float*)d_in[12];
    const float* b_first = (const float*)d_in[13];
    const float* g_first = (const float*)d_in[14];
    const float* be_first= (const float*)d_in[15];
    const float* W_mid   = (const float*)d_in[16];
    const float* b_mid   = (const float*)d_in[17];
    const float* g_mid   = (const float*)d_in[18];
    const float* be_mid  = (const float*)d_in[19];
    const float* W_last  = (const float*)d_in[20];
    const float* b_last  = (const float*)d_in[21];
    const float* g_last  = (const float*)d_in[22];
    const float* be_last = (const float*)d_in[23];
    const float* W_cat   = (const float*)d_in[24];
    const float* b_cat   = (const float*)d_in[25];
    const float* g_cat   = (const float*)d_in[26];
    const float* be_cat  = (const float*)d_in[27];
    float* out = (float*)d_out;

    char* ws = (char*)d_ws;
    size_t off = 0;
    auto carve = [&](size_t bytes) -> char* {
        off = (off + 255) & ~(size_t)255;
        char* p = ws + off;
        off += bytes;
        return p;
    };

    const size_t SB = (size_t)NPAD * 128 * sizeof(bf16_t);
    bf16_t* B[8];
    for (int i = 0; i < 8; ++i) B[i] = (bf16_t*)carve(SB);
    bf16_t* wt    = (bf16_t*)carve((size_t)27 * 16384 * 2);
    float*  partial = (float*)carve((size_t)3 * GRIDG * 256 * sizeof(float));
    float*  tmp   = (float*)carve((size_t)96 * 256 * sizeof(float));
    int* cnts   = (int*)carve(32 * 4);
    int* deg    = (int*)carve((size_t)N_NODES * 4);
    int* rowp   = (int*)carve((size_t)(N_NODES + 1) * 4);
    int* cursor = (int*)carve((size_t)N_NODES * 4);
    int* csr    = (int*)carve((size_t)N_EDGES * 4);
    int* parts  = (int*)carve(SCAN_B * 4);
    int* pofs   = (int*)carve(SCAN_B * 4);

    bf16_t* wtZ  = wt;
    bf16_t* wtF0 = wt + (size_t)3  * 16384;
    bf16_t* wtF1 = wt + (size_t)6  * 16384;
    bf16_t* wtF2 = wt + (size_t)9  * 16384;
    bf16_t* wtM0 = wt + (size_t)12 * 16384;
    bf16_t* wtM1 = wt + (size_t)15 * 16384;
    bf16_t* wtL0 = wt + (size_t)18 * 16384;
    bf16_t* wtL1 = wt + (size_t)21 * 16384;
    bf16_t* wtC  = wt + (size_t)24 * 16384;

    const int GEL8 = (N_NODES * 128) / 2048;   // 6250, exact

    init_zero_kernel<<<dim3((N_NODES + 255) / 256), dim3(256), 0, stream>>>(deg, cnts);
    transpose_w_kernel<<<dim3(1728), dim3(256), 0, stream>>>(W_zero, W_first, W_mid, W_last, W_cat, wt);
    deg_count_kernel<<<dim3((N_EDGES + 255) / 256), dim3(256), 0, stream>>>(e_dst, deg);
    scan_a_kernel<<<dim3(SCAN_B), dim3(256), 0, stream>>>(deg, parts);
    scan_b_kernel<<<dim3(1), dim3(64), 0, stream>>>(parts, pofs);
    scan_c_kernel<<<dim3(SCAN_B), dim3(256), 0, stream>>>(deg, pofs, rowp, cursor);
    scatter_kernel<<<dim3((N_EDGES + 255) / 256), dim3(256), 0, stream>>>(e_src, e_dst, cursor, csr);

    auto M = [&](const bf16_t* x0_, const bf16_t* x1_, const bf16_t* x2_,
                 const bf16_t* w_, const float* b_, const float* g_, const float* be_,
                 const float* wm_, bf16_t* ob_, float* of_, int acc_, int mode_, int id) {
        mixed_kernel<<<dim3(GRIDG), dim3(512), 0, stream>>>(
            x0_, x1_, x2_, w_, b_, g_, be_, wm_, ob_, of_,
            partial, tmp, cnts + id * 2, mode_, acc_);
    };
    auto A = [&](const bf16_t* h_, bf16_t* me_, bf16_t* mx_) {
        agg_kernel<<<dim3(N_NODES / 16), dim3(256), 0, stream>>>(h_, rowp, csr, me_, mx_);
    };

    // zero op: pre -> B3,B4,B5 ; h_in = B6
    pre_kernel<<<dim3(GEL8), dim3(256), 0, stream>>>(src_emb, hr, B[3], B[4], B[5]);
    M(B[3], B[4], B[5], wtZ, b_zero, g_zero, be_zero, w_zero, B[6], nullptr, 0, 0, 0);

    A(B[6], B[3], B[4]);                                             // aggH -> B3,B4

    // s0 = mixed([h_in, aggH], first0)                              // s0 = B5
    M(B[6], B[3], B[4], wtF0, b_first + 0, g_first + 0, be_first + 0,
      w_first + 0, B[5], nullptr, 0, 0, 1);
    // s1 (h_in contribution first)                                  // s1 = B7
    M(B[6], B[3], B[4], wtF1, b_first + 384, g_first + 384, be_first + 384,
      w_first + 3, B[7], nullptr, 0, 0, 2);
    // h_in(B6), aggH(B3,B4) dead

    A(B[5], B[3], B[4]);                                             // aggS0 -> B3,B4

    // s1 += mixed([s0, aggS0], first2)
    M(B[5], B[3], B[4], wtF2, b_first + 768, g_first + 768, be_first + 768,
      w_first + 6, B[7], nullptr, 1, 0, 3);
    // m0 = mixed([s0, aggS0], mid0)                                 // m0 = B6
    M(B[5], B[3], B[4], wtM0, b_mid + 0, g_mid + 0, be_mid + 0,
      w_mid + 0, B[6], nullptr, 0, 0, 4);
    // s0(B5), aggS0(B3,B4) dead

    A(B[7], B[3], B[4]);                                             // aggS1 -> B3,B4

    // m1 = mixed([s1, aggS1], mid1)                                 // m1 = B5
    M(B[7], B[3], B[4], wtM1, b_mid + 384, g_mid + 384, be_mid + 384,
      w_mid + 3, B[5], nullptr, 0, 0, 5);
    // s1(B7), aggS1(B3,B4) dead

    // s_last = mixed([m0, agg m0], last0) + mixed([m1, agg m1], last1)  // sl = B7
    A(B[6], B[3], B[4]);
    M(B[6], B[3], B[4], wtL0, b_last + 0, g_last + 0, be_last + 0,
      w_last + 0, B[7], nullptr, 0, 0, 6);
    A(B[5], B[3], B[4]);
    M(B[5], B[3], B[4], wtL1, b_last + 384, g_last + 384, be_last + 384,
      w_last + 3, B[7], nullptr, 1, 0, 7);

    // out = relu(norm([m0 | m1 | s_last] @ W_cat + b_cat)) directly to fp32
    M(B[6], B[5], B[7], wtC, b_cat, g_cat, be_cat, nullptr,
      nullptr, out, 0, 1, 8);
}

// Round 7
// 1465.356 us; speedup vs baseline: 2.0423x; 2.0423x over previous
//
#include <hip/hip_runtime.h>

#define N_NODES 100000
#define N_EDGES 600000
#define NPAD    100096      // 782 * 128
#define NTILES  782
#define SCAN_B  98          // ceil(100000/1024)
#define EPS_F   1e-5f
#define GRIDG   512         // persistent mixed grid: 2 blocks (8 waves) per CU

typedef __bf16 bf16_t;
typedef __bf16 bf16x8 __attribute__((ext_vector_type(8)));
typedef __bf16 bf16x4 __attribute__((ext_vector_type(4)));
typedef float  f32x4  __attribute__((ext_vector_type(4)));

// ---------------------------------------------------------------------------
// zero deg + grid-barrier counters
__global__ __launch_bounds__(256)
void init_zero_kernel(int* __restrict__ deg, int* __restrict__ cnt)
{
    int i = blockIdx.x * 256 + threadIdx.x;
    if (i < N_NODES) deg[i] = 0;
    if (i < 32) cnt[i] = 0;
}

// ---------------------------------------------------------------------------
// Weight pre-transpose: WT[mat][n][k] = W[mat][k][n], fp32 -> bf16.
__global__ __launch_bounds__(256)
void transpose_w_kernel(const float* __restrict__ Wz, const float* __restrict__ Wf,
                        const float* __restrict__ Wm, const float* __restrict__ Wl,
                        const float* __restrict__ Wc, bf16_t* __restrict__ wt)
{
    int idx = blockIdx.x * 256 + threadIdx.x;      // < 27*16384, exact grid
    int mat = idx >> 14;
    int off = idx & 16383;
    int n = off >> 7, kk = off & 127;
    const float* src;
    if      (mat < 3)  src = Wz + mat * 16384;
    else if (mat < 12) src = Wf + (mat - 3) * 16384;
    else if (mat < 18) src = Wm + (mat - 12) * 16384;
    else if (mat < 24) src = Wl + (mat - 18) * 16384;
    else               src = Wc + (mat - 24) * 16384;
    wt[idx] = (bf16_t)src[kk * 128 + n];
}

// ---------------------------------------------------------------------------
// pre-candidates, vectorized 8 elems/thread: [se, se-hr, se*hr] as bf16
__global__ __launch_bounds__(256)
void pre_kernel(const float* __restrict__ se, const float* __restrict__ hr,
                bf16_t* __restrict__ p0, bf16_t* __restrict__ p1, bf16_t* __restrict__ p2)
{
    long i = ((long)blockIdx.x * 256 + threadIdx.x) * 8;   // grid exact: N*128/2048
    float4 a0 = *(const float4*)&se[i], a1 = *(const float4*)&se[i + 4];
    float4 b0 = *(const float4*)&hr[i], b1 = *(const float4*)&hr[i + 4];
    float av[8] = {a0.x, a0.y, a0.z, a0.w, a1.x, a1.y, a1.z, a1.w};
    float bv[8] = {b0.x, b0.y, b0.z, b0.w, b1.x, b1.y, b1.z, b1.w};
    bf16x8 o0, o1, o2;
#pragma unroll
    for (int j = 0; j < 8; ++j) {
        o0[j] = (bf16_t)av[j];
        o1[j] = (bf16_t)(av[j] - bv[j]);
        o2[j] = (bf16_t)(av[j] * bv[j]);
    }
    *(bf16x8*)&p0[i] = o0;
    *(bf16x8*)&p1[i] = o1;
    *(bf16x8*)&p2[i] = o2;
}

// ---------------------------------------------------------------------------
// CSR build
__global__ __launch_bounds__(256)
void deg_count_kernel(const int* __restrict__ dst, int* __restrict__ deg)
{
    int i = blockIdx.x * 256 + threadIdx.x;
    if (i < N_EDGES) atomicAdd(&deg[dst[i]], 1);
}

__global__ __launch_bounds__(256)
void scan_a_kernel(const int* __restrict__ deg, int* __restrict__ partials)
{
    __shared__ int ls[256];
    int b = blockIdx.x, t = threadIdx.x;
    int s = 0;
    for (int j = 0; j < 4; ++j) {
        int i = b * 1024 + t * 4 + j;
        if (i < N_NODES) s += deg[i];
    }
    ls[t] = s; __syncthreads();
    for (int o = 128; o > 0; o >>= 1) {
        if (t < o) ls[t] += ls[t + o];
        __syncthreads();
    }
    if (t == 0) partials[b] = ls[0];
}

__global__ void scan_b_kernel(const int* __restrict__ partials, int* __restrict__ pofs)
{
    if (threadIdx.x == 0) {
        int a = 0;
        for (int i = 0; i < SCAN_B; ++i) { pofs[i] = a; a += partials[i]; }
    }
}

__global__ __launch_bounds__(256)
void scan_c_kernel(const int* __restrict__ deg, const int* __restrict__ pofs,
                   int* __restrict__ row_ptr, int* __restrict__ cursor)
{
    __shared__ int ls[256];
    int b = blockIdx.x, t = threadIdx.x;
    int v[4], s = 0;
    for (int j = 0; j < 4; ++j) {
        int i = b * 1024 + t * 4 + j;
        v[j] = (i < N_NODES) ? deg[i] : 0;
        s += v[j];
    }
    ls[t] = s; __syncthreads();
    for (int o = 1; o < 256; o <<= 1) {
        int tv = (t >= o) ? ls[t - o] : 0;
        __syncthreads();
        ls[t] += tv;
        __syncthreads();
    }
    int excl = ls[t] - s + pofs[b];
    for (int j = 0; j < 4; ++j) {
        int i = b * 1024 + t * 4 + j;
        if (i < N_NODES) { row_ptr[i] = excl; cursor[i] = excl; excl += v[j]; }
    }
    if (b == 0 && t == 0) row_ptr[N_NODES] = N_EDGES;
}

__global__ __launch_bounds__(256)
void scatter_kernel(const int* __restrict__ src, const int* __restrict__ dst,
                    int* __restrict__ cursor, int* __restrict__ csr_src)
{
    int i = blockIdx.x * 256 + threadIdx.x;
    if (i < N_EDGES) {
        int p = atomicAdd(&cursor[dst[i]], 1);
        csr_src[p] = src[i];
    }
}

// ---------------------------------------------------------------------------
// mean + max aggregation. 16 lanes per node, 16B loads per lane per edge.
__global__ __launch_bounds__(256)
void agg_kernel(const bf16_t* __restrict__ h, const int* __restrict__ row_ptr,
                const int* __restrict__ csr_src,
                bf16_t* __restrict__ mean_o, bf16_t* __restrict__ max_o)
{
    int node = blockIdx.x * 16 + (threadIdx.x >> 4);   // grid exact: N/16
    int dd = (threadIdx.x & 15) * 8;
    int e0 = row_ptr[node], e1 = row_ptr[node + 1];
    float s[8], mx[8];
#pragma unroll
    for (int j = 0; j < 8; ++j) { s[j] = 0.f; mx[j] = 0.f; }
    for (int e = e0; e < e1; ++e) {
        int sc = csr_src[e];
        bf16x8 v = *(const bf16x8*)&h[(long)sc * 128 + dd];
#pragma unroll
        for (int j = 0; j < 8; ++j) {
            float f = (float)v[j];
            s[j] += f;
            mx[j] = fmaxf(mx[j], f);
        }
    }
    float inv = 1.f / fmaxf((float)(e1 - e0), 1.f);
    bf16x8 om, ox;
#pragma unroll
    for (int j = 0; j < 8; ++j) { om[j] = (bf16_t)(s[j] * inv); ox[j] = (bf16_t)mx[j]; }
    *(bf16x8*)&mean_o[(long)node * 128 + dd] = om;
    *(bf16x8*)&max_o [(long)node * 128 + dd] = ox;
}

// ---------------------------------------------------------------------------
// async global->LDS, 16B per lane. LDS dest must be wave-uniform base + lane*16.
__device__ __forceinline__ void gload_lds16(const bf16_t* g, bf16_t* l)
{
    __builtin_amdgcn_global_load_lds(
        (const __attribute__((address_space(1))) void*)g,
        (__attribute__((address_space(3))) void*)l, 16, 0, 0);
}

// lgkm-only barrier: orders LDS writes->reads across waves WITHOUT draining vmcnt.
__device__ __forceinline__ void barrier_lgkm()
{
    asm volatile("s_waitcnt lgkmcnt(0)" ::: "memory");
    __builtin_amdgcn_s_barrier();
    asm volatile("" ::: "memory");
}

// device-wide barrier (R4-proven): RELAXED spin (no per-iteration cache inv),
// one release fence pre-arrival, one acquire fence post-exit, only where used.
// SAFETY: LDS 68.6KB => exactly 2 blocks/CU (LDS-capped); grid==512==2*#CUs;
// VGPR cap via launch_bounds(256,2) = 256 >> actual use => 2 blocks ALWAYS fit
// => all blocks co-resident by construction. Counters pre-zeroed per launch.
__device__ __forceinline__ void grid_bar(int* c, int do_rel, int do_acq)
{
    __syncthreads();
    if (threadIdx.x == 0) {
        if (do_rel) __builtin_amdgcn_fence(__ATOMIC_RELEASE, "agent");
        __hip_atomic_fetch_add(c, 1, __ATOMIC_RELAXED, __HIP_MEMORY_SCOPE_AGENT);
        while (__hip_atomic_load(c, __ATOMIC_RELAXED, __HIP_MEMORY_SCOPE_AGENT) < GRIDG)
            __builtin_amdgcn_s_sleep(16);
        if (do_acq) __builtin_amdgcn_fence(__ATOMIC_ACQUIRE, "agent");
    }
    __syncthreads();
}

// ---------------------------------------------------------------------------
// Fused mixed-op kernel, v4: R0's PROVEN engine (the only one that sustained
// ~2.3 TB/s across 6 rounds: 256 threads, 2x2 waves, acc[4][4], stage W+x
// per item single-buffered, 2 blocks/CU TLP) + fusion (no y materialization).
// R6 lesson encoded: launch_bounds(256,2) -> 256-VGPR cap under EITHER
// waves-per-EU or blocks-per-CU semantics; ~200 VGPR actual => no spill.
// Phase A: per (tile,c) item stage W_c+x_c, MFMA, R0-style lred epilogue
//   writes per-tile (sum,sumsq) partials of RAW acc (bias folded at coef).
// grid_bar -> nk*16-block fold (49 tiles each) -> grid_bar -> coefs in lsc.
// Phase B: tile-aligned recompute, emit state=sum_c relu(A_c*acc+B_c) bf16
//   (mode 0) or final fp32 (mode 1, K=384 chained acc).
__global__ __launch_bounds__(256, 2)
void mixed_kernel(const bf16_t* __restrict__ x0, const bf16_t* __restrict__ x1,
                  const bf16_t* __restrict__ x2, const bf16_t* __restrict__ wt,
                  const float* __restrict__ bias, const float* __restrict__ gg,
                  const float* __restrict__ be, const float* __restrict__ wmix,
                  bf16_t* __restrict__ outb, float* __restrict__ outf,
                  float* __restrict__ partial, float* __restrict__ tmp,
                  int* __restrict__ cnt, int mode, int accflag)
{
    __shared__ __align__(16) bf16_t lds_w[16384];      // W tile (32 KB)
    __shared__ __align__(16) bf16_t lds_x[16384];      // x tile (32 KB)
    __shared__ float lsc[768];                         // lred / coefs (3 KB)

    const int tid  = threadIdx.x;
    const int lane = tid & 63;
    const int wave = tid >> 6;
    const int quad = lane >> 4;
    const int t16  = lane & 15;
    const int wr = wave >> 1, wc = wave & 1;
    const int bid = blockIdx.x;
    const float invN = 1.0f / (float)N_NODES;

    // staging offsets: linear LDS dest, XOR swizzle in the global source
    // (lds[row][c] = G[row][c ^ (row&15)], 2048 chunks, 8 per thread)
    int srcoff[8], dsto[8];
#pragma unroll
    for (int i = 0; i < 8; ++i) {
        int ci = i * 256 + tid;
        int row = ci >> 4, c = ci & 15;
        srcoff[i] = row * 128 + ((c ^ (row & 15)) * 8);
        dsto[i]   = ci * 8;
    }
    auto stage2 = [&](const bf16_t* wsrc, const bf16_t* xsrc) {
#pragma unroll
        for (int i = 0; i < 8; ++i) {
            gload_lds16(wsrc + srcoff[i], &lds_w[dsto[i]]);
            gload_lds16(xsrc + srcoff[i], &lds_x[dsto[i]]);
        }
    };
    auto xp = [&](int c) { return (c == 0) ? x0 : (c == 1) ? x1 : x2; };

    const int ts = (int)(((long)bid * NTILES) / GRIDG);
    const int te = (int)(((long)(bid + 1) * NTILES) / GRIDG);
    const int nk = (mode == 0) ? 3 : 1;

    f32x4 acc[4][4];

#define ZACC() do { \
    _Pragma("unroll") for (int a_ = 0; a_ < 4; ++a_) \
    _Pragma("unroll") for (int b_ = 0; b_ < 4; ++b_) \
        acc[a_][b_] = (f32x4){0.f, 0.f, 0.f, 0.f}; } while (0)

#define MMAC() do { \
    _Pragma("unroll") for (int ks = 0; ks < 4; ++ks) { \
        bf16x8 xf[4], wf[4]; \
        _Pragma("unroll") for (int ms = 0; ms < 4; ++ms) { \
            int row_ = wr * 64 + ms * 16 + t16; \
            int sw_ = (ks * 4 + quad) ^ t16; \
            xf[ms] = *(const bf16x8*)&lds_x[row_ * 128 + sw_ * 8]; \
        } \
        _Pragma("unroll") for (int ns = 0; ns < 4; ++ns) { \
            int row_ = wc * 64 + ns * 16 + t16; \
            int sw_ = (ks * 4 + quad) ^ t16; \
            wf[ns] = *(const bf16x8*)&lds_w[row_ * 128 + sw_ * 8]; \
        } \
        _Pragma("unroll") for (int ns = 0; ns < 4; ++ns) \
        _Pragma("unroll") for (int ms = 0; ms < 4; ++ms) \
            acc[ns][ms] = __builtin_amdgcn_mfma_f32_16x16x32_bf16( \
                wf[ns], xf[ms], acc[ns][ms], 0, 0, 0); \
    } } while (0)

    // R0-style per-item stats epilogue on RAW acc (no bias), partial[pk][tile]
#define STATS(PK, TILE) do { \
    float ss[16], sq[16]; \
    _Pragma("unroll") for (int i = 0; i < 16; ++i) { ss[i] = 0.f; sq[i] = 0.f; } \
    _Pragma("unroll") for (int ms = 0; ms < 4; ++ms) { \
        long m_ = (long)(TILE) * 128 + wr * 64 + ms * 16 + t16; \
        if (m_ < N_NODES) { \
            _Pragma("unroll") for (int ns = 0; ns < 4; ++ns) \
            _Pragma("unroll") for (int j_ = 0; j_ < 4; ++j_) { \
                float v_ = acc[ns][ms][j_]; \
                ss[ns * 4 + j_] += v_; sq[ns * 4 + j_] += v_ * v_; \
            } \
        } \
    } \
    _Pragma("unroll") for (int o = 1; o < 16; o <<= 1) \
    _Pragma("unroll") for (int i = 0; i < 16; ++i) { \
        ss[i] += __shfl_xor(ss[i], o); sq[i] += __shfl_xor(sq[i], o); \
    } \
    if (t16 == 0) { \
        _Pragma("unroll") for (int i = 0; i < 16; ++i) { \
            lsc[wave * 128 + quad * 32 + i]      = ss[i]; \
            lsc[wave * 128 + quad * 32 + 16 + i] = sq[i]; \
        } \
    } \
    barrier_lgkm(); \
    { \
        int d   = tid & 127; \
        int sel = (tid >> 7) * 16; \
        int dwc = d >> 6; \
        int q   = (d >> 2) & 3; \
        int i   = ((d >> 4) & 3) * 4 + (d & 3); \
        float v = lsc[(0 * 2 + dwc) * 128 + q * 32 + sel + i] \
                + lsc[(1 * 2 + dwc) * 128 + q * 32 + sel + i]; \
        partial[((long)(PK) * NTILES + (TILE)) * 256 + tid] = v; \
    } } while (0)

    // ---------------- Phase A: stats only ----------------
    {
        int sA, eA;
        if (mode == 0) {   // item-balanced (items independent)
            sA = (int)(((long)bid * (NTILES * 3)) / GRIDG);
            eA = (int)(((long)(bid + 1) * (NTILES * 3)) / GRIDG);
        } else {           // tile-aligned (acc chained over c)
            sA = ts * 3; eA = te * 3;
        }
#pragma unroll 1
        for (int w = sA; w < eA; ++w) {
            const int c = w % 3, tile = w / 3;
            __syncthreads();                   // prev item's LDS reads done
            stage2(wt + (long)c * 16384, xp(c) + (long)tile * 16384);
            __syncthreads();                   // drains DMA: data ready
            if (mode == 0 || c == 0) ZACC();
            MMAC();
            if (mode == 0) STATS(c, tile);
            else if (c == 2) STATS(0, tile);
        }
    }

    // ---------------- stats fold + coefficients ----------------
    const int foldblk = (bid < nk * 16);
    grid_bar(cnt + 0, 1, foldblk);
    if (foldblk) {                             // level-1 fold: 49 tiles/block
        int k = bid >> 4, j = bid & 15;
        int b0 = j * 49, b1 = (b0 + 49 < NTILES) ? b0 + 49 : NTILES;
        float s = 0.f;
        const float* pp = partial + (long)k * NTILES * 256 + tid;
        for (int b = b0; b < b1; ++b) s += pp[(long)b * 256];
        tmp[(k * 16 + j) * 256 + tid] = s;
    }
    grid_bar(cnt + 1, foldblk, 1);
    if (tid < 128) {                           // per-block coef build
        for (int k = 0; k < nk; ++k) {
            float S = 0.f, Q = 0.f;
#pragma unroll
            for (int j = 0; j < 16; ++j) {
                S += tmp[(k * 16 + j) * 256 + tid];
                Q += tmp[(k * 16 + j) * 256 + 128 + tid];
            }
            float sa  = S * invN;              // mean of raw acc
            float var = Q * invN - sa * sa;    // bias shift: variance unchanged
            float rs  = rsqrtf(var + EPS_F);
            float gk = gg[k * 128 + tid], bek = be[k * 128 + tid];
            float wk = (mode == 0) ? wmix[k] : 1.f;
            lsc[k * 256 + tid]       = wk * rs * gk;              // A
            lsc[k * 256 + 128 + tid] = wk * (-sa * rs * gk + bek);// B (b-mu=-sa)
        }
    }
    __syncthreads();

    // ---------------- Phase B: recompute + emit ----------------
    {
        f32x4 res[4][4];
#pragma unroll 1
        for (int w = ts * 3; w < te * 3; ++w) {
            const int c = w % 3, tile = w / 3;
            __syncthreads();
            stage2(wt + (long)c * 16384, xp(c) + (long)tile * 16384);
            if (mode == 0 && c == 0) {         // res preload overlaps the DMA
                if (accflag) {
#pragma unroll
                    for (int ns = 0; ns < 4; ++ns)
#pragma unroll
                        for (int ms = 0; ms < 4; ++ms) {
                            long m = (long)tile * 128 + wr * 64 + ms * 16 + t16;
                            int n0 = wc * 64 + ns * 16 + quad * 4;
                            bf16x4 pv = *(const bf16x4*)&outb[m * 128 + n0];
                            res[ns][ms] = (f32x4){(float)pv[0], (float)pv[1],
                                                  (float)pv[2], (float)pv[3]};
                        }
                } else {
#pragma unroll
                    for (int a = 0; a < 4; ++a)
#pragma unroll
                        for (int b = 0; b < 4; ++b) res[a][b] = (f32x4){0.f, 0.f, 0.f, 0.f};
                }
            }
            __syncthreads();                   // drains DMA: data ready
            if (mode == 0 || c == 0) ZACC();
            MMAC();

            if (mode == 0) {
#pragma unroll
                for (int ns = 0; ns < 4; ++ns) {
                    int n0 = wc * 64 + ns * 16 + quad * 4;
                    float4 A4 = *(const float4*)&lsc[c * 256 + n0];
                    float4 B4 = *(const float4*)&lsc[c * 256 + 128 + n0];
#pragma unroll
                    for (int ms = 0; ms < 4; ++ms) {
                        res[ns][ms][0] += fmaxf(acc[ns][ms][0] * A4.x + B4.x, 0.f);
                        res[ns][ms][1] += fmaxf(acc[ns][ms][1] * A4.y + B4.y, 0.f);
                        res[ns][ms][2] += fmaxf(acc[ns][ms][2] * A4.z + B4.z, 0.f);
                        res[ns][ms][3] += fmaxf(acc[ns][ms][3] * A4.w + B4.w, 0.f);
                    }
                }
                if (c == 2) {
#pragma unroll
                    for (int ms = 0; ms < 4; ++ms) {
                        long m = (long)tile * 128 + wr * 64 + ms * 16 + t16;
                        if (m < N_NODES) {
#pragma unroll
                            for (int ns = 0; ns < 4; ++ns) {
                                int n0 = wc * 64 + ns * 16 + quad * 4;
                                bf16x4 ov;
                                ov[0] = (bf16_t)res[ns][ms][0];
                                ov[1] = (bf16_t)res[ns][ms][1];
                                ov[2] = (bf16_t)res[ns][ms][2];
                                ov[3] = (bf16_t)res[ns][ms][3];
                                *(bf16x4*)&outb[m * 128 + n0] = ov;
                            }
                        }
                    }
                }
            } else if (c == 2) {
#pragma unroll
                for (int ms = 0; ms < 4; ++ms) {
                    long m = (long)tile * 128 + wr * 64 + ms * 16 + t16;
                    if (m < N_NODES) {
#pragma unroll
                        for (int ns = 0; ns < 4; ++ns) {
                            int n0 = wc * 64 + ns * 16 + quad * 4;
                            float4 A4 = *(const float4*)&lsc[n0];
                            float4 B4 = *(const float4*)&lsc[128 + n0];
                            float4 o;
                            o.x = fmaxf(acc[ns][ms][0] * A4.x + B4.x, 0.f);
                            o.y = fmaxf(acc[ns][ms][1] * A4.y + B4.y, 0.f);
                            o.z = fmaxf(acc[ns][ms][2] * A4.z + B4.z, 0.f);
                            o.w = fmaxf(acc[ns][ms][3] * A4.w + B4.w, 0.f);
                            *(float4*)&outf[m * 128 + n0] = o;
                        }
                    }
                }
            }
        }
    }
#undef ZACC
#undef MMAC
#undef STATS
}

// ---------------------------------------------------------------------------
extern "C" void kernel_launch(void* const* d_in, const int* in_sizes, int n_in,
                              void* d_out, int out_size, void* d_ws, size_t ws_size,
                              hipStream_t stream)
{
    const float* src_emb = (const float*)d_in[0];
    const float* hr      = (const float*)d_in[1];
    const int*   e_src   = (const int*)d_in[2];
    const int*   e_dst   = (const int*)d_in[3];
    const float* w_zero  = (const float*)d_in[4];
    const float* w_first = (const float*)d_in[5];
    const float* w_mid   = (const float*)d_in[6];
    const float* w_last  = (const float*)d_in[7];
    const float* W_zero  = (const float*)d_in[8];
    const float* b_zero  = (const float*)d_in[9];
    const float* g_zero  = (const float*)d_in[10];
    const float* be_zero = (const float*)d_in[11];
    const float* W_first = (const float*)d_in[12];
    const float* b_first = (const float*)d_in[13];
    const float* g_first = (const float*)d_in[14];
    const float* be_first= (const float*)d_in[15];
    const float* W_mid   = (const float*)d_in[16];
    const float* b_mid   = (const float*)d_in[17];
    const float* g_mid   = (const float*)d_in[18];
    const float* be_mid  = (const float*)d_in[19];
    const float* W_last  = (const float*)d_in[20];
    const float* b_last  = (const float*)d_in[21];
    const float* g_last  = (const float*)d_in[22];
    const float* be_last = (const float*)d_in[23];
    const float* W_cat   = (const float*)d_in[24];
    const float* b_cat   = (const float*)d_in[25];
    const float* g_cat   = (const float*)d_in[26];
    const float* be_cat  = (const float*)d_in[27];
    float* out = (float*)d_out;

    char* ws = (char*)d_ws;
    size_t off = 0;
    auto carve = [&](size_t bytes) -> char* {
        off = (off + 255) & ~(size_t)255;
        char* p = ws + off;
        off += bytes;
        return p;
    };

    const size_t SB = (size_t)NPAD * 128 * sizeof(bf16_t);
    bf16_t* B[8];
    for (int i = 0; i < 8; ++i) B[i] = (bf16_t*)carve(SB);
    bf16_t* wt    = (bf16_t*)carve((size_t)27 * 16384 * 2);
    float*  partial = (float*)carve((size_t)3 * NTILES * 256 * sizeof(float));
    float*  tmp   = (float*)carve((size_t)48 * 256 * sizeof(float));
    int* cnts   = (int*)carve(32 * 4);
    int* deg    = (int*)carve((size_t)N_NODES * 4);
    int* rowp   = (int*)carve((size_t)(N_NODES + 1) * 4);
    int* cursor = (int*)carve((size_t)N_NODES * 4);
    int* csr    = (int*)carve((size_t)N_EDGES * 4);
    int* parts  = (int*)carve(SCAN_B * 4);
    int* pofs   = (int*)carve(SCAN_B * 4);

    bf16_t* wtZ  = wt;
    bf16_t* wtF0 = wt + (size_t)3  * 16384;
    bf16_t* wtF1 = wt + (size_t)6  * 16384;
    bf16_t* wtF2 = wt + (size_t)9  * 16384;
    bf16_t* wtM0 = wt + (size_t)12 * 16384;
    bf16_t* wtM1 = wt + (size_t)15 * 16384;
    bf16_t* wtL0 = wt + (size_t)18 * 16384;
    bf16_t* wtL1 = wt + (size_t)21 * 16384;
    bf16_t* wtC  = wt + (size_t)24 * 16384;

    const int GEL8 = (N_NODES * 128) / 2048;   // 6250, exact

    init_zero_kernel<<<dim3((N_NODES + 255) / 256), dim3(256), 0, stream>>>(deg, cnts);
    transpose_w_kernel<<<dim3(1728), dim3(256), 0, stream>>>(W_zero, W_first, W_mid, W_last, W_cat, wt);
    deg_count_kernel<<<dim3((N_EDGES + 255) / 256), dim3(256), 0, stream>>>(e_dst, deg);
    scan_a_kernel<<<dim3(SCAN_B), dim3(256), 0, stream>>>(deg, parts);
    scan_b_kernel<<<dim3(1), dim3(64), 0, stream>>>(parts, pofs);
    scan_c_kernel<<<dim3(SCAN_B), dim3(256), 0, stream>>>(deg, pofs, rowp, cursor);
    scatter_kernel<<<dim3((N_EDGES + 255) / 256), dim3(256), 0, stream>>>(e_src, e_dst, cursor, csr);

    auto M = [&](const bf16_t* x0_, const bf16_t* x1_, const bf16_t* x2_,
                 const bf16_t* w_, const float* b_, const float* g_, const float* be_,
                 const float* wm_, bf16_t* ob_, float* of_, int acc_, int mode_, int id) {
        mixed_kernel<<<dim3(GRIDG), dim3(256), 0, stream>>>(
            x0_, x1_, x2_, w_, b_, g_, be_, wm_, ob_, of_,
            partial, tmp, cnts + id * 2, mode_, acc_);
    };
    auto A = [&](const bf16_t* h_, bf16_t* me_, bf16_t* mx_) {
        agg_kernel<<<dim3(N_NODES / 16), dim3(256), 0, stream>>>(h_, rowp, csr, me_, mx_);
    };

    // zero op: pre -> B3,B4,B5 ; h_in = B6
    pre_kernel<<<dim3(GEL8), dim3(256), 0, stream>>>(src_emb, hr, B[3], B[4], B[5]);
    M(B[3], B[4], B[5], wtZ, b_zero, g_zero, be_zero, w_zero, B[6], nullptr, 0, 0, 0);

    A(B[6], B[3], B[4]);                                             // aggH -> B3,B4

    // s0 = mixed([h_in, aggH], first0)                              // s0 = B5
    M(B[6], B[3], B[4], wtF0, b_first + 0, g_first + 0, be_first + 0,
      w_first + 0, B[5], nullptr, 0, 0, 1);
    // s1 (h_in contribution first)                                  // s1 = B7
    M(B[6], B[3], B[4], wtF1, b_first + 384, g_first + 384, be_first + 384,
      w_first + 3, B[7], nullptr, 0, 0, 2);
    // h_in(B6), aggH(B3,B4) dead

    A(B[5], B[3], B[4]);                                             // aggS0 -> B3,B4

    // s1 += mixed([s0, aggS0], first2)
    M(B[5], B[3], B[4], wtF2, b_first + 768, g_first + 768, be_first + 768,
      w_first + 6, B[7], nullptr, 1, 0, 3);
    // m0 = mixed([s0, aggS0], mid0)                                 // m0 = B6
    M(B[5], B[3], B[4], wtM0, b_mid + 0, g_mid + 0, be_mid + 0,
      w_mid + 0, B[6], nullptr, 0, 0, 4);
    // s0(B5), aggS0(B3,B4) dead

    A(B[7], B[3], B[4]);                                             // aggS1 -> B3,B4

    // m1 = mixed([s1, aggS1], mid1)                                 // m1 = B5
    M(B[7], B[3], B[4], wtM1, b_mid + 384, g_mid + 384, be_mid + 384,
      w_mid + 3, B[5], nullptr, 0, 0, 5);
    // s1(B7), aggS1(B3,B4) dead

    // s_last = mixed([m0, agg m0], last0) + mixed([m1, agg m1], last1)  // sl = B7
    A(B[6], B[3], B[4]);
    M(B[6], B[3], B[4], wtL0, b_last + 0, g_last + 0, be_last + 0,
      w_last + 0, B[7], nullptr, 0, 0, 6);
    A(B[5], B[3], B[4]);
    M(B[5], B[3], B[4], wtL1, b_last + 384, g_last + 384, be_last + 384,
      w_last + 3, B[7], nullptr, 1, 0, 7);

    // out = relu(norm([m0 | m1 | s_last] @ W_cat + b_cat)) directly to fp32
    M(B[6], B[5], B[7], wtC, b_cat, g_cat, be_cat, nullptr,
      nullptr, out, 0, 1, 8);
}

// Round 9
// 1283.954 us; speedup vs baseline: 2.3308x; 1.1413x over previous
//
#include <hip/hip_runtime.h>

#define N_NODES 100000
#define N_EDGES 600000
#define NPAD    100096      // 782 * 128
#define NTILES  782
#define SCAN_B  98          // ceil(100000/1024)
#define EPS_F   1e-5f

typedef __bf16 bf16_t;
typedef __bf16 bf16x8 __attribute__((ext_vector_type(8)));
typedef __bf16 bf16x4 __attribute__((ext_vector_type(4)));
typedef float  f32x4  __attribute__((ext_vector_type(4)));

// ---------------------------------------------------------------------------
// zero deg + stats (9 ops x 768)
__global__ __launch_bounds__(256)
void init_zero_kernel(int* __restrict__ deg, float* __restrict__ stats)
{
    int i = blockIdx.x * 256 + threadIdx.x;
    if (i < N_NODES) deg[i] = 0;
    if (i < 9 * 768) stats[i] = 0.f;
}

// ---------------------------------------------------------------------------
// Weight pre-transpose: WT[mat][n][k] = W[mat][k][n], fp32 -> bf16.
__global__ __launch_bounds__(256)
void transpose_w_kernel(const float* __restrict__ Wz, const float* __restrict__ Wf,
                        const float* __restrict__ Wm, const float* __restrict__ Wl,
                        const float* __restrict__ Wc, bf16_t* __restrict__ wt)
{
    int idx = blockIdx.x * 256 + threadIdx.x;      // < 27*16384, exact grid
    int mat = idx >> 14;
    int off = idx & 16383;
    int n = off >> 7, kk = off & 127;
    const float* src;
    if      (mat < 3)  src = Wz + mat * 16384;
    else if (mat < 12) src = Wf + (mat - 3) * 16384;
    else if (mat < 18) src = Wm + (mat - 12) * 16384;
    else if (mat < 24) src = Wl + (mat - 18) * 16384;
    else               src = Wc + (mat - 24) * 16384;
    wt[idx] = (bf16_t)src[kk * 128 + n];
}

// ---------------------------------------------------------------------------
// pre-candidates, vectorized 8 elems/thread: [se, se-hr, se*hr] as bf16
__global__ __launch_bounds__(256)
void pre_kernel(const float* __restrict__ se, const float* __restrict__ hr,
                bf16_t* __restrict__ p0, bf16_t* __restrict__ p1, bf16_t* __restrict__ p2)
{
    long i = ((long)blockIdx.x * 256 + threadIdx.x) * 8;   // grid exact: N*128/2048
    float4 a0 = *(const float4*)&se[i], a1 = *(const float4*)&se[i + 4];
    float4 b0 = *(const float4*)&hr[i], b1 = *(const float4*)&hr[i + 4];
    float av[8] = {a0.x, a0.y, a0.z, a0.w, a1.x, a1.y, a1.z, a1.w};
    float bv[8] = {b0.x, b0.y, b0.z, b0.w, b1.x, b1.y, b1.z, b1.w};
    bf16x8 o0, o1, o2;
#pragma unroll
    for (int j = 0; j < 8; ++j) {
        o0[j] = (bf16_t)av[j];
        o1[j] = (bf16_t)(av[j] - bv[j]);
        o2[j] = (bf16_t)(av[j] * bv[j]);
    }
    *(bf16x8*)&p0[i] = o0;
    *(bf16x8*)&p1[i] = o1;
    *(bf16x8*)&p2[i] = o2;
}

// ---------------------------------------------------------------------------
// CSR build
__global__ __launch_bounds__(256)
void deg_count_kernel(const int* __restrict__ dst, int* __restrict__ deg)
{
    int i = blockIdx.x * 256 + threadIdx.x;
    if (i < N_EDGES) atomicAdd(&deg[dst[i]], 1);
}

__global__ __launch_bounds__(256)
void scan_a_kernel(const int* __restrict__ deg, int* __restrict__ partials)
{
    __shared__ int ls[256];
    int b = blockIdx.x, t = threadIdx.x;
    int s = 0;
    for (int j = 0; j < 4; ++j) {
        int i = b * 1024 + t * 4 + j;
        if (i < N_NODES) s += deg[i];
    }
    ls[t] = s; __syncthreads();
    for (int o = 128; o > 0; o >>= 1) {
        if (t < o) ls[t] += ls[t + o];
        __syncthreads();
    }
    if (t == 0) partials[b] = ls[0];
}

__global__ void scan_b_kernel(const int* __restrict__ partials, int* __restrict__ pofs)
{
    if (threadIdx.x == 0) {
        int a = 0;
        for (int i = 0; i < SCAN_B; ++i) { pofs[i] = a; a += partials[i]; }
    }
}

__global__ __launch_bounds__(256)
void scan_c_kernel(const int* __restrict__ deg, const int* __restrict__ pofs,
                   int* __restrict__ row_ptr, int* __restrict__ cursor)
{
    __shared__ int ls[256];
    int b = blockIdx.x, t = threadIdx.x;
    int v[4], s = 0;
    for (int j = 0; j < 4; ++j) {
        int i = b * 1024 + t * 4 + j;
        v[j] = (i < N_NODES) ? deg[i] : 0;
        s += v[j];
    }
    ls[t] = s; __syncthreads();
    for (int o = 1; o < 256; o <<= 1) {
        int tv = (t >= o) ? ls[t - o] : 0;
        __syncthreads();
        ls[t] += tv;
        __syncthreads();
    }
    int excl = ls[t] - s + pofs[b];
    for (int j = 0; j < 4; ++j) {
        int i = b * 1024 + t * 4 + j;
        if (i < N_NODES) { row_ptr[i] = excl; cursor[i] = excl; excl += v[j]; }
    }
    if (b == 0 && t == 0) row_ptr[N_NODES] = N_EDGES;
}

__global__ __launch_bounds__(256)
void scatter_kernel(const int* __restrict__ src, const int* __restrict__ dst,
                    int* __restrict__ cursor, int* __restrict__ csr_src)
{
    int i = blockIdx.x * 256 + threadIdx.x;
    if (i < N_EDGES) {
        int p = atomicAdd(&cursor[dst[i]], 1);
        csr_src[p] = src[i];
    }
}

// ---------------------------------------------------------------------------
// mean + max aggregation. 16 lanes per node, 16B loads per lane per edge.
__global__ __launch_bounds__(256)
void agg_kernel(const bf16_t* __restrict__ h, const int* __restrict__ row_ptr,
                const int* __restrict__ csr_src,
                bf16_t* __restrict__ mean_o, bf16_t* __restrict__ max_o)
{
    int node = blockIdx.x * 16 + (threadIdx.x >> 4);   // grid exact: N/16
    int dd = (threadIdx.x & 15) * 8;
    int e0 = row_ptr[node], e1 = row_ptr[node + 1];
    float s[8], mx[8];
#pragma unroll
    for (int j = 0; j < 8; ++j) { s[j] = 0.f; mx[j] = 0.f; }
    for (int e = e0; e < e1; ++e) {
        int sc = csr_src[e];
        bf16x8 v = *(const bf16x8*)&h[(long)sc * 128 + dd];
#pragma unroll
        for (int j = 0; j < 8; ++j) {
            float f = (float)v[j];
            s[j] += f;
            mx[j] = fmaxf(mx[j], f);
        }
    }
    float inv = 1.f / fmaxf((float)(e1 - e0), 1.f);
    bf16x8 om, ox;
#pragma unroll
    for (int j = 0; j < 8; ++j) { om[j] = (bf16_t)(s[j] * inv); ox[j] = (bf16_t)mx[j]; }
    *(bf16x8*)&mean_o[(long)node * 128 + dd] = om;
    *(bf16x8*)&max_o [(long)node * 128 + dd] = ox;
}

// ---------------------------------------------------------------------------
// GEMM phase A: stats only (R0's proven engine: register-staged uint4 with
// LDS-side XOR swizzle, grid (NTILES, nk) — ~3072 waves queued, launch-level
// TLP hides the staging latency; the only engine that sustained 2.35 TB/s).
// NO y store (saves 77 MB vs R0): epilogue reduces RAW acc (no bias) into
// per-tile (sum,sumsq) partials; bias is folded analytically at coef time.
// mode 0: blockIdx.y = k (3 independent GEMMs). mode 1: K=384 cat, 3 chunks.
__global__ __launch_bounds__(256, 2)
void gemmA_kernel(const bf16_t* __restrict__ x0, const bf16_t* __restrict__ x1,
                  const bf16_t* __restrict__ x2, const bf16_t* __restrict__ wt,
                  float* __restrict__ partial, int mode)
{
    __shared__ bf16_t lds_w[16384];
    __shared__ bf16_t lds_x[16384];
    __shared__ float lred[512];
    const int tid  = threadIdx.x;
    const int lane = tid & 63;
    const int wave = tid >> 6;
    const int quad = lane >> 4;
    const int t16  = lane & 15;
    const int wr = wave >> 1, wc = wave & 1;
    const long tile_base = (long)blockIdx.x * 128;

    f32x4 acc[4][4];
#pragma unroll
    for (int a = 0; a < 4; ++a)
#pragma unroll
        for (int b = 0; b < 4; ++b) acc[a][b] = (f32x4){0.f, 0.f, 0.f, 0.f};

    const int k_sel = blockIdx.y;
    const int nchunk = (mode == 0) ? 1 : 3;
    const bf16_t* xk = (k_sel == 0) ? x0 : ((k_sel == 1) ? x1 : x2);

    for (int c3 = 0; c3 < nchunk; ++c3) {
        const bf16_t* xcur = (mode == 0) ? xk : ((c3 == 0) ? x0 : ((c3 == 1) ? x1 : x2));
        const bf16_t* wcur = (mode == 0) ? (wt + k_sel * 16384) : (wt + c3 * 16384);
        if (c3) __syncthreads();
#pragma unroll
        for (int i = 0; i < 8; ++i) {
            int idx = tid + i * 256;
            int row = idx >> 4, c = idx & 15;
            int sw = c ^ (row & 15);
            *(uint4*)&lds_w[row * 128 + sw * 8] = *(const uint4*)&wcur[row * 128 + c * 8];
            *(uint4*)&lds_x[row * 128 + sw * 8] = *(const uint4*)&xcur[(tile_base + row) * 128 + c * 8];
        }
        __syncthreads();
#pragma unroll
        for (int ks = 0; ks < 4; ++ks) {
            bf16x8 xf[4], wf[4];
#pragma unroll
            for (int ms = 0; ms < 4; ++ms) {
                int row = wr * 64 + ms * 16 + t16;
                int sw = (ks * 4 + quad) ^ t16;
                xf[ms] = *(const bf16x8*)&lds_x[row * 128 + sw * 8];
            }
#pragma unroll
            for (int ns = 0; ns < 4; ++ns) {
                int row = wc * 64 + ns * 16 + t16;
                int sw = (ks * 4 + quad) ^ t16;
                wf[ns] = *(const bf16x8*)&lds_w[row * 128 + sw * 8];
            }
#pragma unroll
            for (int ns = 0; ns < 4; ++ns)
#pragma unroll
                for (int ms = 0; ms < 4; ++ms)
                    acc[ns][ms] = __builtin_amdgcn_mfma_f32_16x16x32_bf16(
                        wf[ns], xf[ms], acc[ns][ms], 0, 0, 0);
        }
    }

    // epilogue: per-feature (sum, sumsq) of RAW acc
    float ss[16], sq[16];
#pragma unroll
    for (int i = 0; i < 16; ++i) { ss[i] = 0.f; sq[i] = 0.f; }
#pragma unroll
    for (int ms = 0; ms < 4; ++ms) {
        long m = tile_base + wr * 64 + ms * 16 + t16;
        if (m < N_NODES) {
#pragma unroll
            for (int ns = 0; ns < 4; ++ns)
#pragma unroll
                for (int j = 0; j < 4; ++j) {
                    float v = acc[ns][ms][j];
                    ss[ns * 4 + j] += v;
                    sq[ns * 4 + j] += v * v;
                }
        }
    }
#pragma unroll
    for (int o = 1; o < 16; o <<= 1) {
#pragma unroll
        for (int i = 0; i < 16; ++i) {
            ss[i] += __shfl_xor(ss[i], o);
            sq[i] += __shfl_xor(sq[i], o);
        }
    }
    if (t16 == 0) {
#pragma unroll
        for (int i = 0; i < 16; ++i) {
            lred[wave * 128 + quad * 32 + i]      = ss[i];
            lred[wave * 128 + quad * 32 + 16 + i] = sq[i];
        }
    }
    asm volatile("s_waitcnt lgkmcnt(0)" ::: "memory");
    __builtin_amdgcn_s_barrier();
    {
        int t = tid;                       // t<128: sum of feature t; else sumsq
        int d   = t & 127;
        int sel = (t >> 7) * 16;
        int dwc = d >> 6;
        int q   = (d >> 2) & 3;
        int i   = ((d >> 4) & 3) * 4 + (d & 3);
        float v = lred[(0 * 2 + dwc) * 128 + q * 32 + sel + i]
                + lred[(1 * 2 + dwc) * 128 + q * 32 + sel + i];
        long pidx = ((long)((mode == 0) ? k_sel : 0) * NTILES + blockIdx.x) * 256 + t;
        partial[pidx] = v;
    }
}

// ---------------------------------------------------------------------------
// fold partial[k][782][256] into st[k][256]; grid (nk, 8), 8 atomics/address.
__global__ __launch_bounds__(256)
void reduce_stats_kernel(const float* __restrict__ partial, float* __restrict__ st)
{
    int k = blockIdx.x, j = blockIdx.y, t = threadIdx.x;
    int b0 = j * 98, b1 = (b0 + 98 < NTILES) ? b0 + 98 : NTILES;
    float s = 0.f;
    const float* p = partial + (long)k * NTILES * 256 + t;
    for (int b = b0; b < b1; ++b) s += p[(long)b * 256];
    atomicAdd(&st[k * 256 + t], s);
}

// ---------------------------------------------------------------------------
// per-feature affine coefficients from raw-acc stats:
//   mu_y = mu_raw + b  (bias shift; var unchanged)
//   A = w * rsqrt(var+eps) * g ;  B = w * (-mu_raw * rsqrt * g + be)
// so  w * relu(norm(y)) == relu(A*acc + B)   (w >= 0: U[0,1) weights)
__global__ __launch_bounds__(256)
void coef_kernel(const float* __restrict__ st, const float* __restrict__ bias,
                 const float* __restrict__ gg, const float* __restrict__ be,
                 const float* __restrict__ wmix, float* __restrict__ coef, int mode)
{
    int t = threadIdx.x;
    if (t >= 128) return;
    const float invN = 1.0f / (float)N_NODES;
    int nk = (mode == 0) ? 3 : 1;
    for (int k = 0; k < nk; ++k) {
        float S = st[k * 256 + t], Q = st[k * 256 + 128 + t];
        float sa  = S * invN;
        float var = Q * invN - sa * sa;
        float rs  = rsqrtf(var + EPS_F);
        float gk = gg[k * 128 + t], bek = be[k * 128 + t];
        float wk = (mode == 0) ? wmix[k] : 1.f;
        // NOTE: bias enters mu only; mu_raw already excludes b, and
        // (b - mu_y) = -mu_raw, so B folds bias exactly.
        coef[k * 256 + t]       = wk * rs * gk;
        coef[k * 256 + 128 + t] = wk * (-sa * rs * gk + bek);
        (void)bias;
    }
}

// ---------------------------------------------------------------------------
// GEMM phase B: recompute + emit. grid (NTILES); per tile loop c=0..2 staging
// W_c + x_c (x L3-warm from phase A), MFMA, then:
//   mode 0: res += relu(A_c*acc + B_c) per c; store bf16 state (+= accflag).
//   mode 1: acc chained over c (K=384); store fp32 relu(A*acc+B) final out.
__global__ __launch_bounds__(256, 2)
void gemmB_kernel(const bf16_t* __restrict__ x0, const bf16_t* __restrict__ x1,
                  const bf16_t* __restrict__ x2, const bf16_t* __restrict__ wt,
                  const float* __restrict__ coef, bf16_t* __restrict__ outb,
                  float* __restrict__ outf, int mode, int accflag)
{
    __shared__ bf16_t lds_w[16384];
    __shared__ bf16_t lds_x[16384];
    __shared__ float lsc[768];
    const int tid  = threadIdx.x;
    const int lane = tid & 63;
    const int wave = tid >> 6;
    const int quad = lane >> 4;
    const int t16  = lane & 15;
    const int wr = wave >> 1, wc = wave & 1;
    const long tile_base = (long)blockIdx.x * 128;

    // coefs to LDS (768 floats)
    lsc[tid] = coef[tid];
    if (tid < 256) { lsc[tid + 256] = coef[tid + 256]; lsc[tid + 512] = coef[tid + 512]; }

    f32x4 acc[4][4], res[4][4];
#pragma unroll
    for (int a = 0; a < 4; ++a)
#pragma unroll
        for (int b = 0; b < 4; ++b) acc[a][b] = (f32x4){0.f, 0.f, 0.f, 0.f};

    if (mode == 0 && accflag) {
#pragma unroll
        for (int ns = 0; ns < 4; ++ns)
#pragma unroll
            for (int ms = 0; ms < 4; ++ms) {
                long m = tile_base + wr * 64 + ms * 16 + t16;
                int n0 = wc * 64 + ns * 16 + quad * 4;
                bf16x4 pv = *(const bf16x4*)&outb[(m < N_NODES ? m : 0) * 128 + n0];
                res[ns][ms] = (f32x4){(float)pv[0], (float)pv[1], (float)pv[2], (float)pv[3]};
            }
    } else {
#pragma unroll
        for (int a = 0; a < 4; ++a)
#pragma unroll
            for (int b = 0; b < 4; ++b) res[a][b] = (f32x4){0.f, 0.f, 0.f, 0.f};
    }

    for (int c3 = 0; c3 < 3; ++c3) {
        const bf16_t* xcur = (c3 == 0) ? x0 : ((c3 == 1) ? x1 : x2);
        const bf16_t* wcur = wt + c3 * 16384;
        __syncthreads();                       // prev reads done / coefs visible
#pragma unroll
        for (int i = 0; i < 8; ++i) {
            int idx = tid + i * 256;
            int row = idx >> 4, c = idx & 15;
            int sw = c ^ (row & 15);
            *(uint4*)&lds_w[row * 128 + sw * 8] = *(const uint4*)&wcur[row * 128 + c * 8];
            *(uint4*)&lds_x[row * 128 + sw * 8] = *(const uint4*)&xcur[(tile_base + row) * 128 + c * 8];
        }
        __syncthreads();
        if (mode == 0) {
#pragma unroll
            for (int a = 0; a < 4; ++a)
#pragma unroll
                for (int b = 0; b < 4; ++b) acc[a][b] = (f32x4){0.f, 0.f, 0.f, 0.f};
        }
#pragma unroll
        for (int ks = 0; ks < 4; ++ks) {
            bf16x8 xf[4], wf[4];
#pragma unroll
            for (int ms = 0; ms < 4; ++ms) {
                int row = wr * 64 + ms * 16 + t16;
                int sw = (ks * 4 + quad) ^ t16;
                xf[ms] = *(const bf16x8*)&lds_x[row * 128 + sw * 8];
            }
#pragma unroll
            for (int ns = 0; ns < 4; ++ns) {
                int row = wc * 64 + ns * 16 + t16;
                int sw = (ks * 4 + quad) ^ t16;
                wf[ns] = *(const bf16x8*)&lds_w[row * 128 + sw * 8];
            }
#pragma unroll
            for (int ns = 0; ns < 4; ++ns)
#pragma unroll
                for (int ms = 0; ms < 4; ++ms)
                    acc[ns][ms] = __builtin_amdgcn_mfma_f32_16x16x32_bf16(
                        wf[ns], xf[ms], acc[ns][ms], 0, 0, 0);
        }
        if (mode == 0) {
#pragma unroll
            for (int ns = 0; ns < 4; ++ns) {
                int n0 = wc * 64 + ns * 16 + quad * 4;
                float4 A4 = *(const float4*)&lsc[c3 * 256 + n0];
                float4 B4 = *(const float4*)&lsc[c3 * 256 + 128 + n0];
#pragma unroll
                for (int ms = 0; ms < 4; ++ms) {
                    res[ns][ms][0] += fmaxf(acc[ns][ms][0] * A4.x + B4.x, 0.f);
                    res[ns][ms][1] += fmaxf(acc[ns][ms][1] * A4.y + B4.y, 0.f);
                    res[ns][ms][2] += fmaxf(acc[ns][ms][2] * A4.z + B4.z, 0.f);
                    res[ns][ms][3] += fmaxf(acc[ns][ms][3] * A4.w + B4.w, 0.f);
                }
            }
        }
    }

    if (mode == 0) {
#pragma unroll
        for (int ms = 0; ms < 4; ++ms) {
            long m = tile_base + wr * 64 + ms * 16 + t16;
            if (m < N_NODES) {
#pragma unroll
                for (int ns = 0; ns < 4; ++ns) {
                    int n0 = wc * 64 + ns * 16 + quad * 4;
                    bf16x4 ov;
                    ov[0] = (bf16_t)res[ns][ms][0];
                    ov[1] = (bf16_t)res[ns][ms][1];
                    ov[2] = (bf16_t)res[ns][ms][2];
                    ov[3] = (bf16_t)res[ns][ms][3];
                    *(bf16x4*)&outb[m * 128 + n0] = ov;
                }
            }
        }
    } else {
#pragma unroll
        for (int ms = 0; ms < 4; ++ms) {
            long m = tile_base + wr * 64 + ms * 16 + t16;
            if (m < N_NODES) {
#pragma unroll
                for (int ns = 0; ns < 4; ++ns) {
                    int n0 = wc * 64 + ns * 16 + quad * 4;
                    float4 A4 = *(const float4*)&lsc[n0];
                    float4 B4 = *(const float4*)&lsc[128 + n0];
                    float4 o;
                    o.x = fmaxf(acc[ns][ms][0] * A4.x + B4.x, 0.f);
                    o.y = fmaxf(acc[ns][ms][1] * A4.y + B4.y, 0.f);
                    o.z = fmaxf(acc[ns][ms][2] * A4.z + B4.z, 0.f);
                    o.w = fmaxf(acc[ns][ms][3] * A4.w + B4.w, 0.f);
                    *(float4*)&outf[m * 128 + n0] = o;
                }
            }
        }
    }
}

// ---------------------------------------------------------------------------
extern "C" void kernel_launch(void* const* d_in, const int* in_sizes, int n_in,
                              void* d_out, int out_size, void* d_ws, size_t ws_size,
                              hipStream_t stream)
{
    const float* src_emb = (const float*)d_in[0];
    const float* hr      = (const float*)d_in[1];
    const int*   e_src   = (const int*)d_in[2];
    const int*   e_dst   = (const int*)d_in[3];
    const float* w_zero  = (const float*)d_in[4];
    const float* w_first = (const float*)d_in[5];
    const float* w_mid   = (const float*)d_in[6];
    const float* w_last  = (const float*)d_in[7];
    const float* W_zero  = (const float*)d_in[8];
    const float* b_zero  = (const float*)d_in[9];
    const float* g_zero  = (const float*)d_in[10];
    const float* be_zero = (const float*)d_in[11];
    const float* W_first = (const float*)d_in[12];
    const float* b_first = (const float*)d_in[13];
    const float* g_first = (const float*)d_in[14];
    const float* be_first= (const float*)d_in[15];
    const float* W_mid   = (const float*)d_in[16];
    const float* b_mid   = (const float*)d_in[17];
    const float* g_mid   = (const float*)d_in[18];
    const float* be_mid  = (const float*)d_in[19];
    const float* W_last  = (const float*)d_in[20];
    const float* b_last  = (const float*)d_in[21];
    const float* g_last  = (const float*)d_in[22];
    const float* be_last = (const float*)d_in[23];
    const float* W_cat   = (const float*)d_in[24];
    const float* b_cat   = (const float*)d_in[25];
    const float* g_cat   = (const float*)d_in[26];
    const float* be_cat  = (const float*)d_in[27];
    float* out = (float*)d_out;

    char* ws = (char*)d_ws;
    size_t off = 0;
    auto carve = [&](size_t bytes) -> char* {
        off = (off + 255) & ~(size_t)255;
        char* p = ws + off;
        off += bytes;
        return p;
    };

    const size_t SB = (size_t)NPAD * 128 * sizeof(bf16_t);
    bf16_t* B[8];
    for (int i = 0; i < 8; ++i) B[i] = (bf16_t*)carve(SB);
    bf16_t* wt    = (bf16_t*)carve((size_t)27 * 16384 * 2);
    float*  stats = (float*)carve(9 * 768 * sizeof(float));
    float*  partial = (float*)carve((size_t)3 * NTILES * 256 * sizeof(float));
    float*  coefs = (float*)carve(768 * sizeof(float));
    int* deg    = (int*)carve((size_t)N_NODES * 4);
    int* rowp   = (int*)carve((size_t)(N_NODES + 1) * 4);
    int* cursor = (int*)carve((size_t)N_NODES * 4);
    int* csr    = (int*)carve((size_t)N_EDGES * 4);
    int* parts  = (int*)carve(SCAN_B * 4);
    int* pofs   = (int*)carve(SCAN_B * 4);

    bf16_t* wtZ  = wt;
    bf16_t* wtF0 = wt + (size_t)3  * 16384;
    bf16_t* wtF1 = wt + (size_t)6  * 16384;
    bf16_t* wtF2 = wt + (size_t)9  * 16384;
    bf16_t* wtM0 = wt + (size_t)12 * 16384;
    bf16_t* wtM1 = wt + (size_t)15 * 16384;
    bf16_t* wtL0 = wt + (size_t)18 * 16384;
    bf16_t* wtL1 = wt + (size_t)21 * 16384;
    bf16_t* wtC  = wt + (size_t)24 * 16384;

    const int GEL8 = (N_NODES * 128) / 2048;   // 6250, exact

    init_zero_kernel<<<dim3((N_NODES + 255) / 256), dim3(256), 0, stream>>>(deg, stats);
    transpose_w_kernel<<<dim3(1728), dim3(256), 0, stream>>>(W_zero, W_first, W_mid, W_last, W_cat, wt);
    deg_count_kernel<<<dim3((N_EDGES + 255) / 256), dim3(256), 0, stream>>>(e_dst, deg);
    scan_a_kernel<<<dim3(SCAN_B), dim3(256), 0, stream>>>(deg, parts);
    scan_b_kernel<<<dim3(1), dim3(64), 0, stream>>>(parts, pofs);
    scan_c_kernel<<<dim3(SCAN_B), dim3(256), 0, stream>>>(deg, pofs, rowp, cursor);
    scatter_kernel<<<dim3((N_EDGES + 255) / 256), dim3(256), 0, stream>>>(e_src, e_dst, cursor, csr);

    // fused mixed op = gemmA (stats, no y) -> reduce -> coef -> gemmB (emit)
    auto M = [&](const bf16_t* x0_, const bf16_t* x1_, const bf16_t* x2_,
                 const bf16_t* w_, const float* b_, const float* g_, const float* be_,
                 const float* wm_, bf16_t* ob_, float* of_, float* st_,
                 int acc_, int mode_) {
        int nk = (mode_ == 0) ? 3 : 1;
        gemmA_kernel<<<dim3(NTILES, nk), dim3(256), 0, stream>>>(
            x0_, x1_, x2_, w_, partial, mode_);
        reduce_stats_kernel<<<dim3(nk, 8), dim3(256), 0, stream>>>(partial, st_);
        coef_kernel<<<dim3(1), dim3(256), 0, stream>>>(st_, b_, g_, be_, wm_, coefs, mode_);
        gemmB_kernel<<<dim3(NTILES), dim3(256), 0, stream>>>(
            x0_, x1_, x2_, w_, coefs, ob_, of_, mode_, acc_);
    };
    auto A = [&](const bf16_t* h_, bf16_t* me_, bf16_t* mx_) {
        agg_kernel<<<dim3(N_NODES / 16), dim3(256), 0, stream>>>(h_, rowp, csr, me_, mx_);
    };

    float* st0 = stats + 0 * 768;
    float* st1 = stats + 1 * 768;
    float* st2 = stats + 2 * 768;
    float* st3 = stats + 3 * 768;
    float* st4 = stats + 4 * 768;
    float* st5 = stats + 5 * 768;
    float* st6 = stats + 6 * 768;
    float* st7 = stats + 7 * 768;
    float* st8 = stats + 8 * 768;

    // zero op: pre -> B3,B4,B5 ; h_in = B6
    pre_kernel<<<dim3(GEL8), dim3(256), 0, stream>>>(src_emb, hr, B[3], B[4], B[5]);
    M(B[3], B[4], B[5], wtZ, b_zero, g_zero, be_zero, w_zero, B[6], nullptr, st0, 0, 0);

    A(B[6], B[3], B[4]);                                             // aggH -> B3,B4

    // s0 = mixed([h_in, aggH], first0)                              // s0 = B5
    M(B[6], B[3], B[4], wtF0, b_first + 0, g_first + 0, be_first + 0,
      w_first + 0, B[5], nullptr, st1, 0, 0);
    // s1 (h_in contribution first)                                  // s1 = B7
    M(B[6], B[3], B[4], wtF1, b_first + 384, g_first + 384, be_first + 384,
      w_first + 3, B[7], nullptr, st2, 0, 0);
    // h_in(B6), aggH(B3,B4) dead

    A(B[5], B[3], B[4]);                                             // aggS0 -> B3,B4

    // s1 += mixed([s0, aggS0], first2)
    M(B[5], B[3], B[4], wtF2, b_first + 768, g_first + 768, be_first + 768,
      w_first + 6, B[7], nullptr, st3, 1, 0);
    // m0 = mixed([s0, aggS0], mid0)                                 // m0 = B6
    M(B[5], B[3], B[4], wtM0, b_mid + 0, g_mid + 0, be_mid + 0,
      w_mid + 0, B[6], nullptr, st4, 0, 0);
    // s0(B5), aggS0(B3,B4) dead

    A(B[7], B[3], B[4]);                                             // aggS1 -> B3,B4

    // m1 = mixed([s1, aggS1], mid1)                                 // m1 = B5
    M(B[7], B[3], B[4], wtM1, b_mid + 384, g_mid + 384, be_mid + 384,
      w_mid + 3, B[5], nullptr, st5, 0, 0);
    // s1(B7), aggS1(B3,B4) dead

    // s_last = mixed([m0, agg m0], last0) + mixed([m1, agg m1], last1)  // sl = B7
    A(B[6], B[3], B[4]);
    M(B[6], B[3], B[4], wtL0, b_last + 0, g_last + 0, be_last + 0,
      w_last + 0, B[7], nullptr, st6, 0, 0);
    A(B[5], B[3], B[4]);
    M(B[5], B[3], B[4], wtL1, b_last + 384, g_last + 384, be_last + 384,
      w_last + 3, B[7], nullptr, st7, 1, 0);

    // out = relu(norm([m0 | m1 | s_last] @ W_cat + b_cat)) directly to fp32
    M(B[6], B[5], B[7], wtC, b_cat, g_cat, be_cat, nullptr,
      nullptr, out, st8, 0, 1);
}

// Round 10
// 1281.659 us; speedup vs baseline: 2.3350x; 1.0018x over previous
//
#include <hip/hip_runtime.h>

#define N_NODES 100000
#define N_EDGES 600000
#define NPAD    100096      // 782 * 128
#define NTILES  782
#define SCAN_B  98          // ceil(100000/1024)
#define EPS_F   1e-5f

typedef __bf16 bf16_t;
typedef __bf16 bf16x8 __attribute__((ext_vector_type(8)));
typedef __bf16 bf16x4 __attribute__((ext_vector_type(4)));
typedef float  f32x4  __attribute__((ext_vector_type(4)));

// ---------------------------------------------------------------------------
// shared GEMM-tile macros (reference kernel-local names: tid, wave, quad, t16,
// wr, wc, tile_base, lds_w, lds_x, acc; STATS also lred, partial; FOLD lsc)
#define STAGE_WX(WSRC, XSRC) do { \
    _Pragma("unroll") for (int i_ = 0; i_ < 8; ++i_) { \
        int idx_ = tid + i_ * 256; \
        int row_ = idx_ >> 4, c_ = idx_ & 15; \
        int sw_ = c_ ^ (row_ & 15); \
        *(uint4*)&lds_w[row_ * 128 + sw_ * 8] = *(const uint4*)&(WSRC)[row_ * 128 + c_ * 8]; \
        *(uint4*)&lds_x[row_ * 128 + sw_ * 8] = *(const uint4*)&(XSRC)[(tile_base + row_) * 128 + c_ * 8]; \
    } } while (0)

#define STAGE_W(WSRC) do { \
    _Pragma("unroll") for (int i_ = 0; i_ < 8; ++i_) { \
        int idx_ = tid + i_ * 256; \
        int row_ = idx_ >> 4, c_ = idx_ & 15; \
        int sw_ = c_ ^ (row_ & 15); \
        *(uint4*)&lds_w[row_ * 128 + sw_ * 8] = *(const uint4*)&(WSRC)[row_ * 128 + c_ * 8]; \
    } } while (0)

#define ZACC() do { \
    _Pragma("unroll") for (int a_ = 0; a_ < 4; ++a_) \
    _Pragma("unroll") for (int b_ = 0; b_ < 4; ++b_) \
        acc[a_][b_] = (f32x4){0.f, 0.f, 0.f, 0.f}; } while (0)

#define MMAC() do { \
    _Pragma("unroll") for (int ks = 0; ks < 4; ++ks) { \
        bf16x8 xf[4], wf[4]; \
        _Pragma("unroll") for (int ms = 0; ms < 4; ++ms) { \
            int row_ = wr * 64 + ms * 16 + t16; \
            int sw_ = (ks * 4 + quad) ^ t16; \
            xf[ms] = *(const bf16x8*)&lds_x[row_ * 128 + sw_ * 8]; \
        } \
        _Pragma("unroll") for (int ns = 0; ns < 4; ++ns) { \
            int row_ = wc * 64 + ns * 16 + t16; \
            int sw_ = (ks * 4 + quad) ^ t16; \
            wf[ns] = *(const bf16x8*)&lds_w[row_ * 128 + sw_ * 8]; \
        } \
        _Pragma("unroll") for (int ns = 0; ns < 4; ++ns) \
        _Pragma("unroll") for (int ms = 0; ms < 4; ++ms) \
            acc[ns][ms] = __builtin_amdgcn_mfma_f32_16x16x32_bf16( \
                wf[ns], xf[ms], acc[ns][ms], 0, 0, 0); \
    } } while (0)

// per-feature (sum, sumsq) of RAW acc -> partial[SLICE][blockIdx.x][256]
#define STATS(SLICE) do { \
    float ss[16], sq[16]; \
    _Pragma("unroll") for (int i_ = 0; i_ < 16; ++i_) { ss[i_] = 0.f; sq[i_] = 0.f; } \
    _Pragma("unroll") for (int ms = 0; ms < 4; ++ms) { \
        long m_ = tile_base + wr * 64 + ms * 16 + t16; \
        if (m_ < N_NODES) { \
            _Pragma("unroll") for (int ns = 0; ns < 4; ++ns) \
            _Pragma("unroll") for (int j_ = 0; j_ < 4; ++j_) { \
                float v_ = acc[ns][ms][j_]; \
                ss[ns * 4 + j_] += v_; sq[ns * 4 + j_] += v_ * v_; \
            } \
        } \
    } \
    _Pragma("unroll") for (int o_ = 1; o_ < 16; o_ <<= 1) \
    _Pragma("unroll") for (int i_ = 0; i_ < 16; ++i_) { \
        ss[i_] += __shfl_xor(ss[i_], o_); sq[i_] += __shfl_xor(sq[i_], o_); \
    } \
    if (t16 == 0) { \
        _Pragma("unroll") for (int i_ = 0; i_ < 16; ++i_) { \
            lred[wave * 128 + quad * 32 + i_]      = ss[i_]; \
            lred[wave * 128 + quad * 32 + 16 + i_] = sq[i_]; \
        } \
    } \
    asm volatile("s_waitcnt lgkmcnt(0)" ::: "memory"); \
    __builtin_amdgcn_s_barrier(); \
    { \
        int d_   = tid & 127; \
        int sel_ = (tid >> 7) * 16; \
        int dwc_ = d_ >> 6; \
        int q_   = (d_ >> 2) & 3; \
        int i_   = ((d_ >> 4) & 3) * 4 + (d_ & 3); \
        float v_ = lred[(0 * 2 + dwc_) * 128 + q_ * 32 + sel_ + i_] \
                 + lred[(1 * 2 + dwc_) * 128 + q_ * 32 + sel_ + i_]; \
        partial[((long)(SLICE) * NTILES + blockIdx.x) * 256 + tid] = v_; \
    } } while (0)

// res += relu(A*acc + B) with A,B at lsc[LB .. LB+255]
#define FOLD(RES, LB) do { \
    _Pragma("unroll") for (int ns = 0; ns < 4; ++ns) { \
        int n0_ = wc * 64 + ns * 16 + quad * 4; \
        float4 A4_ = *(const float4*)&lsc[(LB) + n0_]; \
        float4 B4_ = *(const float4*)&lsc[(LB) + 128 + n0_]; \
        _Pragma("unroll") for (int ms = 0; ms < 4; ++ms) { \
            RES[ns][ms][0] += fmaxf(acc[ns][ms][0] * A4_.x + B4_.x, 0.f); \
            RES[ns][ms][1] += fmaxf(acc[ns][ms][1] * A4_.y + B4_.y, 0.f); \
            RES[ns][ms][2] += fmaxf(acc[ns][ms][2] * A4_.z + B4_.z, 0.f); \
            RES[ns][ms][3] += fmaxf(acc[ns][ms][3] * A4_.w + B4_.w, 0.f); \
        } \
    } } while (0)

// coefs from raw-acc stats: A = w*rs*g ; B = w*(-mu_raw*rs*g + be)
// (bias shifts mu only; var unchanged; w>=0 so w*relu(norm) == relu(A*acc+B))
#define COEF_TO_LSC(ST, GG, BE, WK, LB) do { \
    float S_ = (ST)[k_ * 256 + tid], Q_ = (ST)[k_ * 256 + 128 + tid]; \
    float sa_  = S_ * invN; \
    float var_ = Q_ * invN - sa_ * sa_; \
    float rs_  = rsqrtf(var_ + EPS_F); \
    float gk_ = (GG)[k_ * 128 + tid], bek_ = (BE)[k_ * 128 + tid]; \
    lsc[(LB) + k_ * 256 + tid]       = (WK) * rs_ * gk_; \
    lsc[(LB) + k_ * 256 + 128 + tid] = (WK) * (-sa_ * rs_ * gk_ + bek_); \
    } while (0)

// ---------------------------------------------------------------------------
// zero deg + stats (9 ops x 768)
__global__ __launch_bounds__(256)
void init_zero_kernel(int* __restrict__ deg, float* __restrict__ stats)
{
    int i = blockIdx.x * 256 + threadIdx.x;
    if (i < N_NODES) deg[i] = 0;
    if (i < 9 * 768) stats[i] = 0.f;
}

// ---------------------------------------------------------------------------
// Weight pre-transpose: WT[mat][n][k] = W[mat][k][n], fp32 -> bf16.
__global__ __launch_bounds__(256)
void transpose_w_kernel(const float* __restrict__ Wz, const float* __restrict__ Wf,
                        const float* __restrict__ Wm, const float* __restrict__ Wl,
                        const float* __restrict__ Wc, bf16_t* __restrict__ wt)
{
    int idx = blockIdx.x * 256 + threadIdx.x;      // < 27*16384, exact grid
    int mat = idx >> 14;
    int off = idx & 16383;
    int n = off >> 7, kk = off & 127;
    const float* src;
    if      (mat < 3)  src = Wz + mat * 16384;
    else if (mat < 12) src = Wf + (mat - 3) * 16384;
    else if (mat < 18) src = Wm + (mat - 12) * 16384;
    else if (mat < 24) src = Wl + (mat - 18) * 16384;
    else               src = Wc + (mat - 24) * 16384;
    wt[idx] = (bf16_t)src[kk * 128 + n];
}

// ---------------------------------------------------------------------------
// pre-candidates, vectorized 8 elems/thread: [se, se-hr, se*hr] as bf16
__global__ __launch_bounds__(256)
void pre_kernel(const float* __restrict__ se, const float* __restrict__ hr,
                bf16_t* __restrict__ p0, bf16_t* __restrict__ p1, bf16_t* __restrict__ p2)
{
    long i = ((long)blockIdx.x * 256 + threadIdx.x) * 8;   // grid exact: N*128/2048
    float4 a0 = *(const float4*)&se[i], a1 = *(const float4*)&se[i + 4];
    float4 b0 = *(const float4*)&hr[i], b1 = *(const float4*)&hr[i + 4];
    float av[8] = {a0.x, a0.y, a0.z, a0.w, a1.x, a1.y, a1.z, a1.w};
    float bv[8] = {b0.x, b0.y, b0.z, b0.w, b1.x, b1.y, b1.z, b1.w};
    bf16x8 o0, o1, o2;
#pragma unroll
    for (int j = 0; j < 8; ++j) {
        o0[j] = (bf16_t)av[j];
        o1[j] = (bf16_t)(av[j] - bv[j]);
        o2[j] = (bf16_t)(av[j] * bv[j]);
    }
    *(bf16x8*)&p0[i] = o0;
    *(bf16x8*)&p1[i] = o1;
    *(bf16x8*)&p2[i] = o2;
}

// ---------------------------------------------------------------------------
// CSR build
__global__ __launch_bounds__(256)
void deg_count_kernel(const int* __restrict__ dst, int* __restrict__ deg)
{
    int i = blockIdx.x * 256 + threadIdx.x;
    if (i < N_EDGES) atomicAdd(&deg[dst[i]], 1);
}

__global__ __launch_bounds__(256)
void scan_a_kernel(const int* __restrict__ deg, int* __restrict__ partials)
{
    __shared__ int ls[256];
    int b = blockIdx.x, t = threadIdx.x;
    int s = 0;
    for (int j = 0; j < 4; ++j) {
        int i = b * 1024 + t * 4 + j;
        if (i < N_NODES) s += deg[i];
    }
    ls[t] = s; __syncthreads();
    for (int o = 128; o > 0; o >>= 1) {
        if (t < o) ls[t] += ls[t + o];
        __syncthreads();
    }
    if (t == 0) partials[b] = ls[0];
}

__global__ void scan_b_kernel(const int* __restrict__ partials, int* __restrict__ pofs)
{
    if (threadIdx.x == 0) {
        int a = 0;
        for (int i = 0; i < SCAN_B; ++i) { pofs[i] = a; a += partials[i]; }
    }
}

__global__ __launch_bounds__(256)
void scan_c_kernel(const int* __restrict__ deg, const int* __restrict__ pofs,
                   int* __restrict__ row_ptr, int* __restrict__ cursor)
{
    __shared__ int ls[256];
    int b = blockIdx.x, t = threadIdx.x;
    int v[4], s = 0;
    for (int j = 0; j < 4; ++j) {
        int i = b * 1024 + t * 4 + j;
        v[j] = (i < N_NODES) ? deg[i] : 0;
        s += v[j];
    }
    ls[t] = s; __syncthreads();
    for (int o = 1; o < 256; o <<= 1) {
        int tv = (t >= o) ? ls[t - o] : 0;
        __syncthreads();
        ls[t] += tv;
        __syncthreads();
    }
    int excl = ls[t] - s + pofs[b];
    for (int j = 0; j < 4; ++j) {
        int i = b * 1024 + t * 4 + j;
        if (i < N_NODES) { row_ptr[i] = excl; cursor[i] = excl; excl += v[j]; }
    }
    if (b == 0 && t == 0) row_ptr[N_NODES] = N_EDGES;
}

__global__ __launch_bounds__(256)
void scatter_kernel(const int* __restrict__ src, const int* __restrict__ dst,
                    int* __restrict__ cursor, int* __restrict__ csr_src)
{
    int i = blockIdx.x * 256 + threadIdx.x;
    if (i < N_EDGES) {
        int p = atomicAdd(&cursor[dst[i]], 1);
        csr_src[p] = src[i];
    }
}

// ---------------------------------------------------------------------------
// mean + max aggregation. 16 lanes per node, 16B loads per lane per edge.
__global__ __launch_bounds__(256)
void agg_kernel(const bf16_t* __restrict__ h, const int* __restrict__ row_ptr,
                const int* __restrict__ csr_src,
                bf16_t* __restrict__ mean_o, bf16_t* __restrict__ max_o)
{
    int node = blockIdx.x * 16 + (threadIdx.x >> 4);   // grid exact: N/16
    int dd = (threadIdx.x & 15) * 8;
    int e0 = row_ptr[node], e1 = row_ptr[node + 1];
    float s[8], mx[8];
#pragma unroll
    for (int j = 0; j < 8; ++j) { s[j] = 0.f; mx[j] = 0.f; }
    for (int e = e0; e < e1; ++e) {
        int sc = csr_src[e];
        bf16x8 v = *(const bf16x8*)&h[(long)sc * 128 + dd];
#pragma unroll
        for (int j = 0; j < 8; ++j) {
            float f = (float)v[j];
            s[j] += f;
            mx[j] = fmaxf(mx[j], f);
        }
    }
    float inv = 1.f / fmaxf((float)(e1 - e0), 1.f);
    bf16x8 om, ox;
#pragma unroll
    for (int j = 0; j < 8; ++j) { om[j] = (bf16_t)(s[j] * inv); ox[j] = (bf16_t)mx[j]; }
    *(bf16x8*)&mean_o[(long)node * 128 + dd] = om;
    *(bf16x8*)&max_o [(long)node * 128 + dd] = ox;
}

// ---------------------------------------------------------------------------
// GEMM phase A (single op): stats only. R0's proven oversubscribed engine.
// mode 0: grid (NTILES, 3), slice = k_sel. mode 1: grid (NTILES, 1), K=384.
__global__ __launch_bounds__(256, 2)
void gemmA_kernel(const bf16_t* __restrict__ x0, const bf16_t* __restrict__ x1,
                  const bf16_t* __restrict__ x2, const bf16_t* __restrict__ wt,
                  float* __restrict__ partial, int mode)
{
    __shared__ bf16_t lds_w[16384];
    __shared__ bf16_t lds_x[16384];
    __shared__ float lred[512];
    const int tid  = threadIdx.x;
    const int lane = tid & 63;
    const int wave = tid >> 6;
    const int quad = lane >> 4;
    const int t16  = lane & 15;
    const int wr = wave >> 1, wc = wave & 1;
    const long tile_base = (long)blockIdx.x * 128;

    f32x4 acc[4][4];
    ZACC();

    const int k_sel = blockIdx.y;
    const int nchunk = (mode == 0) ? 1 : 3;
    const bf16_t* xk = (k_sel == 0) ? x0 : ((k_sel == 1) ? x1 : x2);

    for (int c3 = 0; c3 < nchunk; ++c3) {
        const bf16_t* xcur = (mode == 0) ? xk : ((c3 == 0) ? x0 : ((c3 == 1) ? x1 : x2));
        const bf16_t* wcur = (mode == 0) ? (wt + k_sel * 16384) : (wt + c3 * 16384);
        if (c3) __syncthreads();
        STAGE_WX(wcur, xcur);
        __syncthreads();
        MMAC();
    }
    STATS((mode == 0) ? k_sel : 0);
}

// ---------------------------------------------------------------------------
// GEMM phase A, PAIRED (two mode-0 ops sharing x): stage x once, two W's,
// two stats epilogues. grid (NTILES, 3). Slices: op a -> k, op b -> 3+k.
__global__ __launch_bounds__(256, 2)
void gemmA2_kernel(const bf16_t* __restrict__ x0, const bf16_t* __restrict__ x1,
                   const bf16_t* __restrict__ x2, const bf16_t* __restrict__ wta,
                   const bf16_t* __restrict__ wtb, float* __restrict__ partial)
{
    __shared__ bf16_t lds_w[16384];
    __shared__ bf16_t lds_x[16384];
    __shared__ float lred[512];
    const int tid  = threadIdx.x;
    const int lane = tid & 63;
    const int wave = tid >> 6;
    const int quad = lane >> 4;
    const int t16  = lane & 15;
    const int wr = wave >> 1, wc = wave & 1;
    const long tile_base = (long)blockIdx.x * 128;

    f32x4 acc[4][4];
    const int k_sel = blockIdx.y;
    const bf16_t* xk = (k_sel == 0) ? x0 : ((k_sel == 1) ? x1 : x2);

    STAGE_WX(wta + k_sel * 16384, xk);
    __syncthreads();
    ZACC();
    MMAC();
    STATS(k_sel);                          // op a -> slice k

    __syncthreads();                       // lred reads + lds_w reads done
    STAGE_W(wtb + k_sel * 16384);          // x stays staged (the pairing win)
    __syncthreads();
    ZACC();
    MMAC();
    STATS(3 + k_sel);                      // op b -> slice 3+k
}

// ---------------------------------------------------------------------------
// fold partial[slice][782][256] into st[slice][256]; grid (nslices, 8).
__global__ __launch_bounds__(256)
void reduce_stats_kernel(const float* __restrict__ partial, float* __restrict__ st)
{
    int k = blockIdx.x, j = blockIdx.y, t = threadIdx.x;
    int b0 = j * 98, b1 = (b0 + 98 < NTILES) ? b0 + 98 : NTILES;
    float s = 0.f;
    const float* p = partial + (long)k * NTILES * 256 + t;
    for (int b = b0; b < b1; ++b) s += p[(long)b * 256];
    atomicAdd(&st[k * 256 + t], s);
}

// ---------------------------------------------------------------------------
// GEMM phase B (single op): coef build inlined (tid<128 from st), recompute,
// emit. mode 0: res += relu per c, store bf16 (+= accflag). mode 1: chained
// acc K=384, store fp32 final out.
__global__ __launch_bounds__(256, 2)
void gemmB_kernel(const bf16_t* __restrict__ x0, const bf16_t* __restrict__ x1,
                  const bf16_t* __restrict__ x2, const bf16_t* __restrict__ wt,
                  const float* __restrict__ st, const float* __restrict__ bias,
                  const float* __restrict__ gg, const float* __restrict__ be,
                  const float* __restrict__ wmix, bf16_t* __restrict__ outb,
                  float* __restrict__ outf, int mode, int accflag)
{
    __shared__ bf16_t lds_w[16384];
    __shared__ bf16_t lds_x[16384];
    __shared__ float lsc[768];
    const int tid  = threadIdx.x;
    const int lane = tid & 63;
    const int wave = tid >> 6;
    const int quad = lane >> 4;
    const int t16  = lane & 15;
    const int wr = wave >> 1, wc = wave & 1;
    const long tile_base = (long)blockIdx.x * 128;
    const float invN = 1.0f / (float)N_NODES;

    // coef prologue (barrier provided by first chunk's __syncthreads)
    if (tid < 128) {
        int nk = (mode == 0) ? 3 : 1;
        for (int k_ = 0; k_ < nk; ++k_) {
            float wk = (mode == 0) ? wmix[k_] : 1.f;
            COEF_TO_LSC(st, gg, be, wk, 0);
        }
    }
    (void)bias;

    f32x4 acc[4][4], res[4][4];
    ZACC();

    if (mode == 0 && accflag) {
#pragma unroll
        for (int ns = 0; ns < 4; ++ns)
#pragma unroll
            for (int ms = 0; ms < 4; ++ms) {
                long m = tile_base + wr * 64 + ms * 16 + t16;
                int n0 = wc * 64 + ns * 16 + quad * 4;
                bf16x4 pv = *(const bf16x4*)&outb[(m < N_NODES ? m : 0) * 128 + n0];
                res[ns][ms] = (f32x4){(float)pv[0], (float)pv[1], (float)pv[2], (float)pv[3]};
            }
    } else {
#pragma unroll
        for (int a = 0; a < 4; ++a)
#pragma unroll
            for (int b = 0; b < 4; ++b) res[a][b] = (f32x4){0.f, 0.f, 0.f, 0.f};
    }

    for (int c3 = 0; c3 < 3; ++c3) {
        const bf16_t* xcur = (c3 == 0) ? x0 : ((c3 == 1) ? x1 : x2);
        const bf16_t* wcur = wt + c3 * 16384;
        __syncthreads();                   // prev reads done / coefs visible
        STAGE_WX(wcur, xcur);
        __syncthreads();
        if (mode == 0) ZACC();
        MMAC();
        if (mode == 0) FOLD(res, c3 * 256);
    }

    if (mode == 0) {
#pragma unroll
        for (int ms = 0; ms < 4; ++ms) {
            long m = tile_base + wr * 64 + ms * 16 + t16;
            if (m < N_NODES) {
#pragma unroll
                for (int ns = 0; ns < 4; ++ns) {
                    int n0 = wc * 64 + ns * 16 + quad * 4;
                    bf16x4 ov;
                    ov[0] = (bf16_t)res[ns][ms][0];
                    ov[1] = (bf16_t)res[ns][ms][1];
                    ov[2] = (bf16_t)res[ns][ms][2];
                    ov[3] = (bf16_t)res[ns][ms][3];
                    *(bf16x4*)&outb[m * 128 + n0] = ov;
                }
            }
        }
    } else {
#pragma unroll
        for (int ms = 0; ms < 4; ++ms) {
            long m = tile_base + wr * 64 + ms * 16 + t16;
            if (m < N_NODES) {
#pragma unroll
                for (int ns = 0; ns < 4; ++ns) {
                    int n0 = wc * 64 + ns * 16 + quad * 4;
                    float4 A4 = *(const float4*)&lsc[n0];
                    float4 B4 = *(const float4*)&lsc[128 + n0];
                    float4 o;
                    o.x = fmaxf(acc[ns][ms][0] * A4.x + B4.x, 0.f);
                    o.y = fmaxf(acc[ns][ms][1] * A4.y + B4.y, 0.f);
                    o.z = fmaxf(acc[ns][ms][2] * A4.z + B4.z, 0.f);
                    o.w = fmaxf(acc[ns][ms][3] * A4.w + B4.w, 0.f);
                    *(float4*)&outf[m * 128 + n0] = o;
                }
            }
        }
    }
}

// ---------------------------------------------------------------------------
// GEMM phase B, PAIRED (two mode-0 ops sharing x): per chunk stage x once,
// W_a -> MFMA -> fold res_a, W_b -> MFMA -> fold res_b. Two output tiles.
// ~190 VGPR + AGPR acc; no min-wave cap so no forced-spill (R6 lesson);
// 2 blocks/CU by LDS (70 KB) if regs fit, else 1 (slower, still correct).
__global__ __launch_bounds__(256)
void gemmB2_kernel(const bf16_t* __restrict__ x0, const bf16_t* __restrict__ x1,
                   const bf16_t* __restrict__ x2, const bf16_t* __restrict__ wta,
                   const bf16_t* __restrict__ wtb,
                   const float* __restrict__ sta, const float* __restrict__ stb,
                   const float* __restrict__ gga, const float* __restrict__ bea,
                   const float* __restrict__ wma,
                   const float* __restrict__ ggb, const float* __restrict__ beb,
                   const float* __restrict__ wmb,
                   bf16_t* __restrict__ outa, bf16_t* __restrict__ outbb,
                   int acca, int accb)
{
    __shared__ bf16_t lds_w[16384];
    __shared__ bf16_t lds_x[16384];
    __shared__ float lsc[1536];
    const int tid  = threadIdx.x;
    const int lane = tid & 63;
    const int wave = tid >> 6;
    const int quad = lane >> 4;
    const int t16  = lane & 15;
    const int wr = wave >> 1, wc = wave & 1;
    const long tile_base = (long)blockIdx.x * 128;
    const float invN = 1.0f / (float)N_NODES;

    if (tid < 128) {
        for (int k_ = 0; k_ < 3; ++k_) {
            COEF_TO_LSC(sta, gga, bea, wma[k_], 0);
            COEF_TO_LSC(stb, ggb, beb, wmb[k_], 768);
        }
    }

    f32x4 acc[4][4], resa[4][4], resb[4][4];
    ZACC();

#pragma unroll
    for (int ns = 0; ns < 4; ++ns)
#pragma unroll
        for (int ms = 0; ms < 4; ++ms) {
            long m = tile_base + wr * 64 + ms * 16 + t16;
            long mc = (m < N_NODES ? m : 0);
            int n0 = wc * 64 + ns * 16 + quad * 4;
            if (acca) {
                bf16x4 pv = *(const bf16x4*)&outa[mc * 128 + n0];
                resa[ns][ms] = (f32x4){(float)pv[0], (float)pv[1], (float)pv[2], (float)pv[3]};
            } else resa[ns][ms] = (f32x4){0.f, 0.f, 0.f, 0.f};
            if (accb) {
                bf16x4 pv = *(const bf16x4*)&outbb[mc * 128 + n0];
                resb[ns][ms] = (f32x4){(float)pv[0], (float)pv[1], (float)pv[2], (float)pv[3]};
            } else resb[ns][ms] = (f32x4){0.f, 0.f, 0.f, 0.f};
        }

    for (int c3 = 0; c3 < 3; ++c3) {
        const bf16_t* xcur = (c3 == 0) ? x0 : ((c3 == 1) ? x1 : x2);
        __syncthreads();                   // prev reads done / coefs visible
        STAGE_WX(wta + c3 * 16384, xcur);
        __syncthreads();
        ZACC();
        MMAC();
        FOLD(resa, c3 * 256);
        __syncthreads();                   // lds_w reads done across waves
        STAGE_W(wtb + c3 * 16384);         // x stays staged
        __syncthreads();
        ZACC();
        MMAC();
        FOLD(resb, 768 + c3 * 256);
    }

#pragma unroll
    for (int ms = 0; ms < 4; ++ms) {
        long m = tile_base + wr * 64 + ms * 16 + t16;
        if (m < N_NODES) {
#pragma unroll
            for (int ns = 0; ns < 4; ++ns) {
                int n0 = wc * 64 + ns * 16 + quad * 4;
                bf16x4 ova, ovb;
                ova[0] = (bf16_t)resa[ns][ms][0]; ova[1] = (bf16_t)resa[ns][ms][1];
                ova[2] = (bf16_t)resa[ns][ms][2]; ova[3] = (bf16_t)resa[ns][ms][3];
                ovb[0] = (bf16_t)resb[ns][ms][0]; ovb[1] = (bf16_t)resb[ns][ms][1];
                ovb[2] = (bf16_t)resb[ns][ms][2]; ovb[3] = (bf16_t)resb[ns][ms][3];
                *(bf16x4*)&outa [m * 128 + n0] = ova;
                *(bf16x4*)&outbb[m * 128 + n0] = ovb;
            }
        }
    }
}

// ---------------------------------------------------------------------------
extern "C" void kernel_launch(void* const* d_in, const int* in_sizes, int n_in,
                              void* d_out, int out_size, void* d_ws, size_t ws_size,
                              hipStream_t stream)
{
    const float* src_emb = (const float*)d_in[0];
    const float* hr      = (const float*)d_in[1];
    const int*   e_src   = (const int*)d_in[2];
    const int*   e_dst   = (const int*)d_in[3];
    const float* w_zero  = (const float*)d_in[4];
    const float* w_first = (const float*)d_in[5];
    const float* w_mid   = (const float*)d_in[6];
    const float* w_last  = (const float*)d_in[7];
    const float* W_zero  = (const float*)d_in[8];
    const float* b_zero  = (const float*)d_in[9];
    const float* g_zero  = (const float*)d_in[10];
    const float* be_zero = (const float*)d_in[11];
    const float* W_first = (const float*)d_in[12];
    const float* b_first = (const float*)d_in[13];
    const float* g_first = (const float*)d_in[14];
    const float* be_first= (const float*)d_in[15];
    const float* W_mid   = (const float*)d_in[16];
    const float* b_mid   = (const float*)d_in[17];
    const float* g_mid   = (const float*)d_in[18];
    const float* be_mid  = (const float*)d_in[19];
    const float* W_last  = (const float*)d_in[20];
    const float* b_last  = (const float*)d_in[21];
    const float* g_last  = (const float*)d_in[22];
    const float* be_last = (const float*)d_in[23];
    const float* W_cat   = (const float*)d_in[24];
    const float* b_cat   = (const float*)d_in[25];
    const float* g_cat   = (const float*)d_in[26];
    const float* be_cat  = (const float*)d_in[27];
    float* out = (float*)d_out;

    char* ws = (char*)d_ws;
    size_t off = 0;
    auto carve = [&](size_t bytes) -> char* {
        off = (off + 255) & ~(size_t)255;
        char* p = ws + off;
        off += bytes;
        return p;
    };

    const size_t SB = (size_t)NPAD * 128 * sizeof(bf16_t);
    bf16_t* B[8];
    for (int i = 0; i < 8; ++i) B[i] = (bf16_t*)carve(SB);
    bf16_t* wt    = (bf16_t*)carve((size_t)27 * 16384 * 2);
    float*  stats = (float*)carve(9 * 768 * sizeof(float));
    float*  partial = (float*)carve((size_t)6 * NTILES * 256 * sizeof(float));
    int* deg    = (int*)carve((size_t)N_NODES * 4);
    int* rowp   = (int*)carve((size_t)(N_NODES + 1) * 4);
    int* cursor = (int*)carve((size_t)N_NODES * 4);
    int* csr    = (int*)carve((size_t)N_EDGES * 4);
    int* parts  = (int*)carve(SCAN_B * 4);
    int* pofs   = (int*)carve(SCAN_B * 4);

    bf16_t* wtZ  = wt;
    bf16_t* wtF0 = wt + (size_t)3  * 16384;
    bf16_t* wtF1 = wt + (size_t)6  * 16384;
    bf16_t* wtF2 = wt + (size_t)9  * 16384;
    bf16_t* wtM0 = wt + (size_t)12 * 16384;
    bf16_t* wtM1 = wt + (size_t)15 * 16384;
    bf16_t* wtL0 = wt + (size_t)18 * 16384;
    bf16_t* wtL1 = wt + (size_t)21 * 16384;
    bf16_t* wtC  = wt + (size_t)24 * 16384;

    float* st0 = stats + 0 * 768;
    float* st1 = stats + 1 * 768;
    float* st2 = stats + 2 * 768;
    float* st3 = stats + 3 * 768;
    float* st4 = stats + 4 * 768;
    float* st5 = stats + 5 * 768;
    float* st6 = stats + 6 * 768;
    float* st7 = stats + 7 * 768;
    float* st8 = stats + 8 * 768;

    const int GEL8 = (N_NODES * 128) / 2048;   // 6250, exact

    init_zero_kernel<<<dim3((N_NODES + 255) / 256), dim3(256), 0, stream>>>(deg, stats);
    transpose_w_kernel<<<dim3(1728), dim3(256), 0, stream>>>(W_zero, W_first, W_mid, W_last, W_cat, wt);
    deg_count_kernel<<<dim3((N_EDGES + 255) / 256), dim3(256), 0, stream>>>(e_dst, deg);
    scan_a_kernel<<<dim3(SCAN_B), dim3(256), 0, stream>>>(deg, parts);
    scan_b_kernel<<<dim3(1), dim3(64), 0, stream>>>(parts, pofs);
    scan_c_kernel<<<dim3(SCAN_B), dim3(256), 0, stream>>>(deg, pofs, rowp, cursor);
    scatter_kernel<<<dim3((N_EDGES + 255) / 256), dim3(256), 0, stream>>>(e_src, e_dst, cursor, csr);

    auto A = [&](const bf16_t* h_, bf16_t* me_, bf16_t* mx_) {
        agg_kernel<<<dim3(N_NODES / 16), dim3(256), 0, stream>>>(h_, rowp, csr, me_, mx_);
    };
    // single fused op
    auto M = [&](const bf16_t* x0_, const bf16_t* x1_, const bf16_t* x2_,
                 const bf16_t* w_, const float* b_, const float* g_, const float* be_,
                 const float* wm_, bf16_t* ob_, float* of_, float* st_,
                 int acc_, int mode_) {
        int nk = (mode_ == 0) ? 3 : 1;
        gemmA_kernel<<<dim3(NTILES, nk), dim3(256), 0, stream>>>(
            x0_, x1_, x2_, w_, partial, mode_);
        reduce_stats_kernel<<<dim3(nk, 8), dim3(256), 0, stream>>>(partial, st_);
        gemmB_kernel<<<dim3(NTILES), dim3(256), 0, stream>>>(
            x0_, x1_, x2_, w_, st_, b_, g_, be_, wm_, ob_, of_, mode_, acc_);
    };
    // paired fused ops (same x, sta/stb must be CONTIGUOUS st slices)
    auto M2 = [&](const bf16_t* x0_, const bf16_t* x1_, const bf16_t* x2_,
                  const bf16_t* wa_, const bf16_t* wb_, float* sta_, float* stb_,
                  const float* ga_, const float* bea_, const float* wma_,
                  const float* gb_, const float* beb_, const float* wmb_,
                  bf16_t* oa_, bf16_t* ob_, int acca_, int accb_) {
        gemmA2_kernel<<<dim3(NTILES, 3), dim3(256), 0, stream>>>(
            x0_, x1_, x2_, wa_, wb_, partial);
        reduce_stats_kernel<<<dim3(6, 8), dim3(256), 0, stream>>>(partial, sta_);
        gemmB2_kernel<<<dim3(NTILES), dim3(256), 0, stream>>>(
            x0_, x1_, x2_, wa_, wb_, sta_, stb_,
            ga_, bea_, wma_, gb_, beb_, wmb_, oa_, ob_, acca_, accb_);
    };

    // zero op: pre -> B3,B4,B5 ; h_in = B6
    pre_kernel<<<dim3(GEL8), dim3(256), 0, stream>>>(src_emb, hr, B[3], B[4], B[5]);
    M(B[3], B[4], B[5], wtZ, b_zero, g_zero, be_zero, w_zero, B[6], nullptr, st0, 0, 0);

    A(B[6], B[3], B[4]);                                             // aggH -> B3,B4

    // F0 -> s0 (B5, fresh) and F1 -> s1 (B7, fresh): same x = [B6,B3,B4]
    M2(B[6], B[3], B[4], wtF0, wtF1, st1, st2,
       g_first + 0,   be_first + 0,   w_first + 0,
       g_first + 384, be_first + 384, w_first + 3,
       B[5], B[7], 0, 0);
    // h_in(B6) stays (needed? no — dead), aggH(B3,B4) dead

    A(B[5], B[3], B[4]);                                             // aggS0 -> B3,B4

    // F2 -> s1 += (B7, acc) and M0 -> m0 (B6, fresh): same x = [B5,B3,B4]
    M2(B[5], B[3], B[4], wtF2, wtM0, st3, st4,
       g_first + 768, be_first + 768, w_first + 6,
       g_mid + 0,     be_mid + 0,     w_mid + 0,
       B[7], B[6], 1, 0);
    // s0(B5), aggS0(B3,B4) dead

    A(B[7], B[3], B[4]);                                             // aggS1 -> B3,B4

    // m1 = mixed([s1, aggS1], mid1)                                 // m1 = B5
    M(B[7], B[3], B[4], wtM1, b_mid + 384, g_mid + 384, be_mid + 384,
      w_mid + 3, B[5], nullptr, st5, 0, 0);
    // s1(B7), aggS1(B3,B4) dead

    // s_last = mixed([m0, agg m0], last0) + mixed([m1, agg m1], last1)  // sl = B7
    A(B[6], B[3], B[4]);
    M(B[6], B[3], B[4], wtL0, b_last + 0, g_last + 0, be_last + 0,
      w_last + 0, B[7], nullptr, st6, 0, 0);
    A(B[5], B[3], B[4]);
    M(B[5], B[3], B[4], wtL1, b_last + 384, g_last + 384, be_last + 384,
      w_last + 3, B[7], nullptr, st7, 1, 0);

    // out = relu(norm([m0 | m1 | s_last] @ W_cat + b_cat)) directly to fp32
    M(B[6], B[5], B[7], wtC, b_cat, g_cat, be_cat, nullptr,
      nullptr, out, st8, 0, 1);
}

// Round 11
// 1159.461 us; speedup vs baseline: 2.5810x; 1.1054x over previous
//
#include <hip/hip_runtime.h>

#define N_NODES 100000
#define N_EDGES 600000
#define NPAD    100096      // 782 * 128
#define NTILES  782
#define SCAN_B  98          // ceil(100000/1024)
#define EPS_F   1e-5f
#define GRIDG   256         // persistent mixed grid: 1 block (8 waves) per CU

typedef __bf16 bf16_t;
typedef __bf16 bf16x8 __attribute__((ext_vector_type(8)));
typedef __bf16 bf16x4 __attribute__((ext_vector_type(4)));
typedef float  f32x4  __attribute__((ext_vector_type(4)));

// ---------------------------------------------------------------------------
// zero deg + grid-barrier counters
__global__ __launch_bounds__(256)
void init_zero_kernel(int* __restrict__ deg, int* __restrict__ cnt)
{
    int i = blockIdx.x * 256 + threadIdx.x;
    if (i < N_NODES) deg[i] = 0;
    if (i < 32) cnt[i] = 0;
}

// ---------------------------------------------------------------------------
// Weight pre-transpose: WT[mat][n][k] = W[mat][k][n], fp32 -> bf16.
__global__ __launch_bounds__(256)
void transpose_w_kernel(const float* __restrict__ Wz, const float* __restrict__ Wf,
                        const float* __restrict__ Wm, const float* __restrict__ Wl,
                        const float* __restrict__ Wc, bf16_t* __restrict__ wt)
{
    int idx = blockIdx.x * 256 + threadIdx.x;      // < 27*16384, exact grid
    int mat = idx >> 14;
    int off = idx & 16383;
    int n = off >> 7, kk = off & 127;
    const float* src;
    if      (mat < 3)  src = Wz + mat * 16384;
    else if (mat < 12) src = Wf + (mat - 3) * 16384;
    else if (mat < 18) src = Wm + (mat - 12) * 16384;
    else if (mat < 24) src = Wl + (mat - 18) * 16384;
    else               src = Wc + (mat - 24) * 16384;
    wt[idx] = (bf16_t)src[kk * 128 + n];
}

// ---------------------------------------------------------------------------
// pre-candidates, vectorized 8 elems/thread: [se, se-hr, se*hr] as bf16
__global__ __launch_bounds__(256)
void pre_kernel(const float* __restrict__ se, const float* __restrict__ hr,
                bf16_t* __restrict__ p0, bf16_t* __restrict__ p1, bf16_t* __restrict__ p2)
{
    long i = ((long)blockIdx.x * 256 + threadIdx.x) * 8;   // grid exact: N*128/2048
    float4 a0 = *(const float4*)&se[i], a1 = *(const float4*)&se[i + 4];
    float4 b0 = *(const float4*)&hr[i], b1 = *(const float4*)&hr[i + 4];
    float av[8] = {a0.x, a0.y, a0.z, a0.w, a1.x, a1.y, a1.z, a1.w};
    float bv[8] = {b0.x, b0.y, b0.z, b0.w, b1.x, b1.y, b1.z, b1.w};
    bf16x8 o0, o1, o2;
#pragma unroll
    for (int j = 0; j < 8; ++j) {
        o0[j] = (bf16_t)av[j];
        o1[j] = (bf16_t)(av[j] - bv[j]);
        o2[j] = (bf16_t)(av[j] * bv[j]);
    }
    *(bf16x8*)&p0[i] = o0;
    *(bf16x8*)&p1[i] = o1;
    *(bf16x8*)&p2[i] = o2;
}

// ---------------------------------------------------------------------------
// CSR build
__global__ __launch_bounds__(256)
void deg_count_kernel(const int* __restrict__ dst, int* __restrict__ deg)
{
    int i = blockIdx.x * 256 + threadIdx.x;
    if (i < N_EDGES) atomicAdd(&deg[dst[i]], 1);
}

__global__ __launch_bounds__(256)
void scan_a_kernel(const int* __restrict__ deg, int* __restrict__ partials)
{
    __shared__ int ls[256];
    int b = blockIdx.x, t = threadIdx.x;
    int s = 0;
    for (int j = 0; j < 4; ++j) {
        int i = b * 1024 + t * 4 + j;
        if (i < N_NODES) s += deg[i];
    }
    ls[t] = s; __syncthreads();
    for (int o = 128; o > 0; o >>= 1) {
        if (t < o) ls[t] += ls[t + o];
        __syncthreads();
    }
    if (t == 0) partials[b] = ls[0];
}

__global__ void scan_b_kernel(const int* __restrict__ partials, int* __restrict__ pofs)
{
    if (threadIdx.x == 0) {
        int a = 0;
        for (int i = 0; i < SCAN_B; ++i) { pofs[i] = a; a += partials[i]; }
    }
}

__global__ __launch_bounds__(256)
void scan_c_kernel(const int* __restrict__ deg, const int* __restrict__ pofs,
                   int* __restrict__ row_ptr, int* __restrict__ cursor)
{
    __shared__ int ls[256];
    int b = blockIdx.x, t = threadIdx.x;
    int v[4], s = 0;
    for (int j = 0; j < 4; ++j) {
        int i = b * 1024 + t * 4 + j;
        v[j] = (i < N_NODES) ? deg[i] : 0;
        s += v[j];
    }
    ls[t] = s; __syncthreads();
    for (int o = 1; o < 256; o <<= 1) {
        int tv = (t >= o) ? ls[t - o] : 0;
        __syncthreads();
        ls[t] += tv;
        __syncthreads();
    }
    int excl = ls[t] - s + pofs[b];
    for (int j = 0; j < 4; ++j) {
        int i = b * 1024 + t * 4 + j;
        if (i < N_NODES) { row_ptr[i] = excl; cursor[i] = excl; excl += v[j]; }
    }
    if (b == 0 && t == 0) row_ptr[N_NODES] = N_EDGES;
}

__global__ __launch_bounds__(256)
void scatter_kernel(const int* __restrict__ src, const int* __restrict__ dst,
                    int* __restrict__ cursor, int* __restrict__ csr_src)
{
    int i = blockIdx.x * 256 + threadIdx.x;
    if (i < N_EDGES) {
        int p = atomicAdd(&cursor[dst[i]], 1);
        csr_src[p] = src[i];
    }
}

// ---------------------------------------------------------------------------
// mean + max aggregation. 16 lanes per node, 16B loads per lane per edge.
__global__ __launch_bounds__(256)
void agg_kernel(const bf16_t* __restrict__ h, const int* __restrict__ row_ptr,
                const int* __restrict__ csr_src,
                bf16_t* __restrict__ mean_o, bf16_t* __restrict__ max_o)
{
    int node = blockIdx.x * 16 + (threadIdx.x >> 4);   // grid exact: N/16
    int dd = (threadIdx.x & 15) * 8;
    int e0 = row_ptr[node], e1 = row_ptr[node + 1];
    float s[8], mx[8];
#pragma unroll
    for (int j = 0; j < 8; ++j) { s[j] = 0.f; mx[j] = 0.f; }
    for (int e = e0; e < e1; ++e) {
        int sc = csr_src[e];
        bf16x8 v = *(const bf16x8*)&h[(long)sc * 128 + dd];
#pragma unroll
        for (int j = 0; j < 8; ++j) {
            float f = (float)v[j];
            s[j] += f;
            mx[j] = fmaxf(mx[j], f);
        }
    }
    float inv = 1.f / fmaxf((float)(e1 - e0), 1.f);
    bf16x8 om, ox;
#pragma unroll
    for (int j = 0; j < 8; ++j) { om[j] = (bf16_t)(s[j] * inv); ox[j] = (bf16_t)mx[j]; }
    *(bf16x8*)&mean_o[(long)node * 128 + dd] = om;
    *(bf16x8*)&max_o [(long)node * 128 + dd] = ox;
}

// ---------------------------------------------------------------------------
// async global->LDS, 16B per lane. LDS dest must be wave-uniform base + lane*16.
__device__ __forceinline__ void gload_lds16(const bf16_t* g, bf16_t* l)
{
    __builtin_amdgcn_global_load_lds(
        (const __attribute__((address_space(1))) void*)g,
        (__attribute__((address_space(3))) void*)l, 16, 0, 0);
}

// lgkm-only barrier: orders LDS writes->reads across waves WITHOUT draining vmcnt.
__device__ __forceinline__ void barrier_lgkm()
{
    asm volatile("s_waitcnt lgkmcnt(0)" ::: "memory");
    __builtin_amdgcn_s_barrier();
    asm volatile("" ::: "memory");
}

// device-wide barrier (R4-proven): RELAXED spin (no per-iteration cache inv),
// one release fence pre-arrival, one acquire fence post-exit, only where used.
// SAFETY: LDS > 80KB => 1 block/CU; grid == 256 == #CUs => co-resident by
// construction. Counters pre-zeroed per launch.
__device__ __forceinline__ void grid_bar(int* c, int do_rel, int do_acq)
{
    __syncthreads();
    if (threadIdx.x == 0) {
        if (do_rel) __builtin_amdgcn_fence(__ATOMIC_RELEASE, "agent");
        __hip_atomic_fetch_add(c, 1, __ATOMIC_RELAXED, __HIP_MEMORY_SCOPE_AGENT);
        while (__hip_atomic_load(c, __ATOMIC_RELAXED, __HIP_MEMORY_SCOPE_AGENT) < GRIDG)
            __builtin_amdgcn_s_sleep(16);
        if (do_acq) __builtin_amdgcn_fence(__ATOMIC_ACQUIRE, "agent");
    }
    __syncthreads();
}

// ---------------------------------------------------------------------------
// Fused mixed-op kernel (session-best config, 1163us @ R5; resubmitted with
// one fix: phase-B res preload now issued BEFORE the prefetch stage, so the
// compiler's wait for res does not drain the in-flight DMA ring — vmcnt
// retires in order, waiting for the OLDER res loads keeps the NEWER stage
// loads outstanding).
//   - x ring of 4 x 32KB LDS slots; loop top vmcnt(8/4/0)+barrier; stage w+3.
//   - W in registers (wreg[3][2][4]; VGPR 128 total measured, no spill).
//   - stats in registers: ssA/sqA accumulate RAW acc (bias folded at coef
//     build: mu_y = mu_raw + b, var unchanged; w>=0 so w*relu(norm)=relu(A*y+B)).
// Phase A: stats (mode 0: item-balanced; mode 1: tile-aligned, acc chained).
// grid_bar -> nk*16-block fold -> grid_bar -> coefs in lsc.
// Phase B: tile-major recompute, emit state = sum_c relu(A_c*acc+B_c) bf16
// (mode 0) or final fp32 (mode 1).
__global__ __launch_bounds__(512, 1)
void mixed_kernel(const bf16_t* __restrict__ x0, const bf16_t* __restrict__ x1,
                  const bf16_t* __restrict__ x2, const bf16_t* __restrict__ wt,
                  const float* __restrict__ bias, const float* __restrict__ gg,
                  const float* __restrict__ be, const float* __restrict__ wmix,
                  bf16_t* __restrict__ outb, float* __restrict__ outf,
                  float* __restrict__ partial, float* __restrict__ tmp,
                  int* __restrict__ cnt, int mode, int accflag)
{
    __shared__ __align__(16) bf16_t lds_x[4][16384];   // x ring (4 x 32 KB)
    __shared__ float lsc[768];                         // lred / coefs

    const int tid  = threadIdx.x;
    const int lane = tid & 63;
    const int w8   = tid >> 6;
    const int quad = lane >> 4;
    const int t16  = lane & 15;
    const int wr = w8 >> 2, wc = w8 & 3;
    const int bid = blockIdx.x;
    const float invN = 1.0f / (float)N_NODES;

    // staging offsets: linear LDS dest, XOR swizzle in the global source
    int srcoff[4], dsto[4];
#pragma unroll
    for (int i = 0; i < 4; ++i) {
        int ci = i * 512 + tid;
        int row = ci >> 4, c = ci & 15;
        srcoff[i] = row * 128 + ((c ^ (row & 15)) * 8);
        dsto[i]   = ci * 8;
    }
    auto stage = [&](const bf16_t* src, int slot) {
#pragma unroll
        for (int i = 0; i < 4; ++i)
            gload_lds16(src + srcoff[i], &lds_x[slot][dsto[i]]);
    };
    auto xp = [&](int c) { return (c == 0) ? x0 : (c == 1) ? x1 : x2; };

    // W fragments to registers (global, L2-hot; swizzle-free layout)
    bf16x8 wreg[3][2][4];
#pragma unroll
    for (int c = 0; c < 3; ++c)
#pragma unroll
        for (int ns = 0; ns < 2; ++ns)
#pragma unroll
            for (int ks = 0; ks < 4; ++ks)
                wreg[c][ns][ks] = *(const bf16x8*)
                    &wt[(long)c * 16384 + (wc * 32 + ns * 16 + t16) * 128
                        + ks * 32 + quad * 8];

    const int ts = (int)(((long)bid * NTILES) / GRIDG);
    const int te = (int)(((long)(bid + 1) * NTILES) / GRIDG);
    const int nk = (mode == 0) ? 3 : 1;

    f32x4 acc[2][4];
    float ssA[3][8], sqA[3][8];
#pragma unroll
    for (int k = 0; k < 3; ++k)
#pragma unroll
        for (int i = 0; i < 8; ++i) { ssA[k][i] = 0.f; sqA[k][i] = 0.f; }

#define ZACC() do { \
    _Pragma("unroll") for (int a_ = 0; a_ < 2; ++a_) \
    _Pragma("unroll") for (int b_ = 0; b_ < 4; ++b_) \
        acc[a_][b_] = (f32x4){0.f, 0.f, 0.f, 0.f}; } while (0)

#define MMAC(C) do { \
    _Pragma("unroll") for (int ks = 0; ks < 4; ++ks) { \
        bf16x8 xf[4]; \
        _Pragma("unroll") for (int ms = 0; ms < 4; ++ms) { \
            int row_ = wr * 64 + ms * 16 + t16; \
            int sw_ = (ks * 4 + quad) ^ t16; \
            xf[ms] = *(const bf16x8*)&lds_x[slot][row_ * 128 + sw_ * 8]; \
        } \
        _Pragma("unroll") for (int ns = 0; ns < 2; ++ns) \
        _Pragma("unroll") for (int ms = 0; ms < 4; ++ms) \
            acc[ns][ms] = __builtin_amdgcn_mfma_f32_16x16x32_bf16( \
                wreg[C][ns][ks], xf[ms], acc[ns][ms], 0, 0, 0); \
    } } while (0)

#define ACCST(K) do { \
    _Pragma("unroll") for (int ms = 0; ms < 4; ++ms) { \
        long m_ = (long)tile * 128 + wr * 64 + ms * 16 + t16; \
        if (m_ < N_NODES) { \
            _Pragma("unroll") for (int ns = 0; ns < 2; ++ns) \
            _Pragma("unroll") for (int j_ = 0; j_ < 4; ++j_) { \
                float v_ = acc[ns][ms][j_]; \
                ssA[K][ns * 4 + j_] += v_; \
                sqA[K][ns * 4 + j_] += v_ * v_; \
            } \
        } \
    } } while (0)

#define RINGWAIT(w_, e_) do { \
    int ah_ = (e_) - 1 - (w_); \
    if (ah_ >= 2)      asm volatile("s_waitcnt vmcnt(8)" ::: "memory"); \
    else if (ah_ == 1) asm volatile("s_waitcnt vmcnt(4)" ::: "memory"); \
    else               asm volatile("s_waitcnt vmcnt(0)" ::: "memory"); \
    __builtin_amdgcn_sched_barrier(0); \
    __builtin_amdgcn_s_barrier(); \
    __builtin_amdgcn_sched_barrier(0); } while (0)

    // ---------------- Phase A: stats only ----------------
    {
        int sA, eA;
        if (mode == 0) {   // item-balanced (items independent)
            sA = (int)(((long)bid * (NTILES * 3)) / GRIDG);
            eA = (int)(((long)(bid + 1) * (NTILES * 3)) / GRIDG);
        } else {           // tile-aligned (acc chained over c)
            sA = ts * 3; eA = te * 3;
        }
#pragma unroll 1
        for (int i = 0; i < 3; ++i)
            if (sA + i < eA) stage(xp((sA + i) % 3) + (long)((sA + i) / 3) * 16384,
                                   (sA + i) & 3);
#pragma unroll 1
        for (int w = sA; w < eA; ++w) {
            const int c = w % 3, tile = w / 3, slot = w & 3;
            RINGWAIT(w, eA);
            if (w + 3 < eA)
                stage(xp((w + 3) % 3) + (long)((w + 3) / 3) * 16384, (w + 3) & 3);
            if (mode == 0 || c == 0) ZACC();
            if (c == 0) MMAC(0); else if (c == 1) MMAC(1); else MMAC(2);
            if (mode == 0) {
                if (c == 0) ACCST(0); else if (c == 1) ACCST(1); else ACCST(2);
            } else if (c == 2) ACCST(0);
        }
    }

    // block-level stats reduce: shfl over the 16 lanes of each t16 group
#pragma unroll
    for (int o = 1; o < 16; o <<= 1)
#pragma unroll
        for (int k = 0; k < 3; ++k)
#pragma unroll
            for (int i = 0; i < 8; ++i) {
                ssA[k][i] += __shfl_xor(ssA[k][i], o);
                sqA[k][i] += __shfl_xor(sqA[k][i], o);
            }
#pragma unroll 1
    for (int k = 0; k < nk; ++k) {
        barrier_lgkm();                        // lsc reuse fence
        if (t16 == 0) {
#pragma unroll
            for (int ns = 0; ns < 2; ++ns)
#pragma unroll
                for (int i = 0; i < 4; ++i) {
                    float s_, q_;
                    if (k == 0)      { s_ = ssA[0][ns*4+i]; q_ = sqA[0][ns*4+i]; }
                    else if (k == 1) { s_ = ssA[1][ns*4+i]; q_ = sqA[1][ns*4+i]; }
                    else             { s_ = ssA[2][ns*4+i]; q_ = sqA[2][ns*4+i]; }
                    lsc[w8 * 64 +      ns * 16 + quad * 4 + i] = s_;
                    lsc[w8 * 64 + 32 + ns * 16 + quad * 4 + i] = q_;
                }
        }
        barrier_lgkm();
        if (tid < 256) {
            int selo = (tid >> 7) * 32;
            int d = tid & 127;
            int wcq = d >> 5, f = d & 31;
            float v = lsc[wcq * 64 + selo + f] + lsc[(wcq + 4) * 64 + selo + f];
            partial[((long)k * GRIDG + bid) * 256 + tid] = v;
        }
    }

    // ---------------- stats fold + coefficients ----------------
    const int foldblk = (bid < nk * 16);
    grid_bar(cnt + 0, 1, foldblk);
    if (foldblk && tid < 256) {                // sum 16 block-rows each
        int k = bid >> 4, j = bid & 15;
        float s = 0.f;
        const float* pp = partial + ((long)k * GRIDG + j * 16) * 256 + tid;
#pragma unroll
        for (int b = 0; b < 16; ++b) s += pp[(long)b * 256];
        tmp[(k * 16 + j) * 256 + tid] = s;
    }
    grid_bar(cnt + 1, foldblk, 1);
    if (tid < 128) {                           // per-block coef build
        for (int k = 0; k < nk; ++k) {
            float S = 0.f, Q = 0.f;
#pragma unroll
            for (int j = 0; j < 16; ++j) {
                S += tmp[(k * 16 + j) * 256 + tid];
                Q += tmp[(k * 16 + j) * 256 + 128 + tid];
            }
            float sa  = S * invN;              // mean of raw acc
            float var = Q * invN - sa * sa;    // bias shift: variance unchanged
            float rs  = rsqrtf(var + EPS_F);
            float gk = gg[k * 128 + tid], bek = be[k * 128 + tid];
            float bk = bias[k * 128 + tid];
            float wk = (mode == 0) ? wmix[k] : 1.f;
            lsc[k * 256 + tid]       = wk * rs * gk;
            lsc[k * 256 + 128 + tid] = wk * (-sa * rs * gk + bek);
            (void)bk;
        }
    }
    __syncthreads();

    // ---------------- Phase B: recompute + emit ----------------
    {
        const int w0 = ts * 3, w1 = te * 3;
        f32x4 res[2][4];
#pragma unroll 1
        for (int i = 0; i < 3; ++i)
            if (w0 + i < w1) stage(xp((w0 + i) % 3) + (long)((w0 + i) / 3) * 16384,
                                   (w0 + i) & 3);
#pragma unroll 1
        for (int w = w0; w < w1; ++w) {
            const int c = w % 3, tile = w / 3, slot = w & 3;
            RINGWAIT(w, w1);
            // res preload BEFORE the prefetch issue: its wait then leaves the
            // newer stage loads in flight (in-order vmcnt retirement).
            if (mode == 0 && c == 0) {
                if (accflag) {
#pragma unroll
                    for (int ns = 0; ns < 2; ++ns)
#pragma unroll
                        for (int ms = 0; ms < 4; ++ms) {
                            long m = (long)tile * 128 + wr * 64 + ms * 16 + t16;
                            int n0 = wc * 32 + ns * 16 + quad * 4;
                            bf16x4 pv = *(const bf16x4*)&outb[m * 128 + n0];
                            res[ns][ms] = (f32x4){(float)pv[0], (float)pv[1],
                                                  (float)pv[2], (float)pv[3]};
                        }
                } else {
#pragma unroll
                    for (int a = 0; a < 2; ++a)
#pragma unroll
                        for (int b = 0; b < 4; ++b) res[a][b] = (f32x4){0.f, 0.f, 0.f, 0.f};
                }
            }
            if (w + 3 < w1)
                stage(xp((w + 3) % 3) + (long)((w + 3) / 3) * 16384, (w + 3) & 3);
            if (mode == 0 || c == 0) ZACC();
            if (c == 0) MMAC(0); else if (c == 1) MMAC(1); else MMAC(2);

            if (mode == 0) {
#pragma unroll
                for (int ns = 0; ns < 2; ++ns) {
                    int n0 = wc * 32 + ns * 16 + quad * 4;
                    float4 A4 = *(const float4*)&lsc[c * 256 + n0];
                    float4 B4 = *(const float4*)&lsc[c * 256 + 128 + n0];
#pragma unroll
                    for (int ms = 0; ms < 4; ++ms) {
                        res[ns][ms][0] += fmaxf(acc[ns][ms][0] * A4.x + B4.x, 0.f);
                        res[ns][ms][1] += fmaxf(acc[ns][ms][1] * A4.y + B4.y, 0.f);
                        res[ns][ms][2] += fmaxf(acc[ns][ms][2] * A4.z + B4.z, 0.f);
                        res[ns][ms][3] += fmaxf(acc[ns][ms][3] * A4.w + B4.w, 0.f);
                    }
                }
                if (c == 2) {
#pragma unroll
                    for (int ms = 0; ms < 4; ++ms) {
                        long m = (long)tile * 128 + wr * 64 + ms * 16 + t16;
                        if (m < N_NODES) {
#pragma unroll
                            for (int ns = 0; ns < 2; ++ns) {
                                int n0 = wc * 32 + ns * 16 + quad * 4;
                                bf16x4 ov;
                                ov[0] = (bf16_t)res[ns][ms][0];
                                ov[1] = (bf16_t)res[ns][ms][1];
                                ov[2] = (bf16_t)res[ns][ms][2];
                                ov[3] = (bf16_t)res[ns][ms][3];
                                *(bf16x4*)&outb[m * 128 + n0] = ov;
                            }
                        }
                    }
                }
            } else if (c == 2) {
#pragma unroll
                for (int ms = 0; ms < 4; ++ms) {
                    long m = (long)tile * 128 + wr * 64 + ms * 16 + t16;
                    if (m < N_NODES) {
#pragma unroll
                        for (int ns = 0; ns < 2; ++ns) {
                            int n0 = wc * 32 + ns * 16 + quad * 4;
                            float4 A4 = *(const float4*)&lsc[n0];
                            float4 B4 = *(const float4*)&lsc[128 + n0];
                            float4 o;
                            o.x = fmaxf(acc[ns][ms][0] * A4.x + B4.x, 0.f);
                            o.y = fmaxf(acc[ns][ms][1] * A4.y + B4.y, 0.f);
                            o.z = fmaxf(acc[ns][ms][2] * A4.z + B4.z, 0.f);
                            o.w = fmaxf(acc[ns][ms][3] * A4.w + B4.w, 0.f);
                            *(float4*)&outf[m * 128 + n0] = o;
                        }
                    }
                }
            }
        }
    }
#undef ZACC
#undef MMAC
#undef ACCST
#undef RINGWAIT
}

// ---------------------------------------------------------------------------
extern "C" void kernel_launch(void* const* d_in, const int* in_sizes, int n_in,
                              void* d_out, int out_size, void* d_ws, size_t ws_size,
                              hipStream_t stream)
{
    const float* src_emb = (const float*)d_in[0];
    const float* hr      = (const float*)d_in[1];
    const int*   e_src   = (const int*)d_in[2];
    const int*   e_dst   = (const int*)d_in[3];
    const float* w_zero  = (const float*)d_in[4];
    const float* w_first = (const float*)d_in[5];
    const float* w_mid   = (const float*)d_in[6];
    const float* w_last  = (const float*)d_in[7];
    const float* W_zero  = (const float*)d_in[8];
    const float* b_zero  = (const float*)d_in[9];
    const float* g_zero  = (const float*)d_in[10];
    const float* be_zero = (const float*)d_in[11];
    const float* W_first = (const float*)d_in[12];
    const float* b_first = (const float*)d_in[13];
    const float* g_first = (const float*)d_in[14];
    const float* be_first= (const float*)d_in[15];
    const float* W_mid   = (const float*)d_in[16];
    const float* b_mid   = (const float*)d_in[17];
    const float* g_mid   = (const float*)d_in[18];
    const float* be_mid  = (const float*)d_in[19];
    const float* W_last  = (const float*)d_in[20];
    const float* b_last  = (const float*)d_in[21];
    const float* g_last  = (const float*)d_in[22];
    const float* be_last = (const float*)d_in[23];
    const float* W_cat   = (const float*)d_in[24];
    const float* b_cat   = (const float*)d_in[25];
    const float* g_cat   = (const float*)d_in[26];
    const float* be_cat  = (const float*)d_in[27];
    float* out = (float*)d_out;

    char* ws = (char*)d_ws;
    size_t off = 0;
    auto carve = [&](size_t bytes) -> char* {
        off = (off + 255) & ~(size_t)255;
        char* p = ws + off;
        off += bytes;
        return p;
    };

    const size_t SB = (size_t)NPAD * 128 * sizeof(bf16_t);
    bf16_t* B[8];
    for (int i = 0; i < 8; ++i) B[i] = (bf16_t*)carve(SB);
    bf16_t* wt    = (bf16_t*)carve((size_t)27 * 16384 * 2);
    float*  partial = (float*)carve((size_t)3 * GRIDG * 256 * sizeof(float));
    float*  tmp   = (float*)carve((size_t)48 * 256 * sizeof(float));
    int* cnts   = (int*)carve(32 * 4);
    int* deg    = (int*)carve((size_t)N_NODES * 4);
    int* rowp   = (int*)carve((size_t)(N_NODES + 1) * 4);
    int* cursor = (int*)carve((size_t)N_NODES * 4);
    int* csr    = (int*)carve((size_t)N_EDGES * 4);
    int* parts  = (int*)carve(SCAN_B * 4);
    int* pofs   = (int*)carve(SCAN_B * 4);

    bf16_t* wtZ  = wt;
    bf16_t* wtF0 = wt + (size_t)3  * 16384;
    bf16_t* wtF1 = wt + (size_t)6  * 16384;
    bf16_t* wtF2 = wt + (size_t)9  * 16384;
    bf16_t* wtM0 = wt + (size_t)12 * 16384;
    bf16_t* wtM1 = wt + (size_t)15 * 16384;
    bf16_t* wtL0 = wt + (size_t)18 * 16384;
    bf16_t* wtL1 = wt + (size_t)21 * 16384;
    bf16_t* wtC  = wt + (size_t)24 * 16384;

    const int GEL8 = (N_NODES * 128) / 2048;   // 6250, exact

    init_zero_kernel<<<dim3((N_NODES + 255) / 256), dim3(256), 0, stream>>>(deg, cnts);
    transpose_w_kernel<<<dim3(1728), dim3(256), 0, stream>>>(W_zero, W_first, W_mid, W_last, W_cat, wt);
    deg_count_kernel<<<dim3((N_EDGES + 255) / 256), dim3(256), 0, stream>>>(e_dst, deg);
    scan_a_kernel<<<dim3(SCAN_B), dim3(256), 0, stream>>>(deg, parts);
    scan_b_kernel<<<dim3(1), dim3(64), 0, stream>>>(parts, pofs);
    scan_c_kernel<<<dim3(SCAN_B), dim3(256), 0, stream>>>(deg, pofs, rowp, cursor);
    scatter_kernel<<<dim3((N_EDGES + 255) / 256), dim3(256), 0, stream>>>(e_src, e_dst, cursor, csr);

    auto M = [&](const bf16_t* x0_, const bf16_t* x1_, const bf16_t* x2_,
                 const bf16_t* w_, const float* b_, const float* g_, const float* be_,
                 const float* wm_, bf16_t* ob_, float* of_, int acc_, int mode_, int id) {
        mixed_kernel<<<dim3(GRIDG), dim3(512), 0, stream>>>(
            x0_, x1_, x2_, w_, b_, g_, be_, wm_, ob_, of_,
            partial, tmp, cnts + id * 2, mode_, acc_);
    };
    auto A = [&](const bf16_t* h_, bf16_t* me_, bf16_t* mx_) {
        agg_kernel<<<dim3(N_NODES / 16), dim3(256), 0, stream>>>(h_, rowp, csr, me_, mx_);
    };

    // zero op: pre -> B3,B4,B5 ; h_in = B6
    pre_kernel<<<dim3(GEL8), dim3(256), 0, stream>>>(src_emb, hr, B[3], B[4], B[5]);
    M(B[3], B[4], B[5], wtZ, b_zero, g_zero, be_zero, w_zero, B[6], nullptr, 0, 0, 0);

    A(B[6], B[3], B[4]);                                             // aggH -> B3,B4

    // s0 = mixed([h_in, aggH], first0)                              // s0 = B5
    M(B[6], B[3], B[4], wtF0, b_first + 0, g_first + 0, be_first + 0,
      w_first + 0, B[5], nullptr, 0, 0, 1);
    // s1 (h_in contribution first)                                  // s1 = B7
    M(B[6], B[3], B[4], wtF1, b_first + 384, g_first + 384, be_first + 384,
      w_first + 3, B[7], nullptr, 0, 0, 2);
    // h_in(B6), aggH(B3,B4) dead

    A(B[5], B[3], B[4]);                                             // aggS0 -> B3,B4

    // s1 += mixed([s0, aggS0], first2)
    M(B[5], B[3], B[4], wtF2, b_first + 768, g_first + 768, be_first + 768,
      w_first + 6, B[7], nullptr, 1, 0, 3);
    // m0 = mixed([s0, aggS0], mid0)                                 // m0 = B6
    M(B[5], B[3], B[4], wtM0, b_mid + 0, g_mid + 0, be_mid + 0,
      w_mid + 0, B[6], nullptr, 0, 0, 4);
    // s0(B5), aggS0(B3,B4) dead

    A(B[7], B[3], B[4]);                                             // aggS1 -> B3,B4

    // m1 = mixed([s1, aggS1], mid1)                                 // m1 = B5
    M(B[7], B[3], B[4], wtM1, b_mid + 384, g_mid + 384, be_mid + 384,
      w_mid + 3, B[5], nullptr, 0, 0, 5);
    // s1(B7), aggS1(B3,B4) dead

    // s_last = mixed([m0, agg m0], last0) + mixed([m1, agg m1], last1)  // sl = B7
    A(B[6], B[3], B[4]);
    M(B[6], B[3], B[4], wtL0, b_last + 0, g_last + 0, be_last + 0,
      w_last + 0, B[7], nullptr, 0, 0, 6);
    A(B[5], B[3], B[4]);
    M(B[5], B[3], B[4], wtL1, b_last + 384, g_last + 384, be_last + 384,
      w_last + 3, B[7], nullptr, 1, 0, 7);

    // out = relu(norm([m0 | m1 | s_last] @ W_cat + b_cat)) directly to fp32
    M(B[6], B[5], B[7], wtC, b_cat, g_cat, be_cat, nullptr,
      nullptr, out, 0, 1, 8);
}